// Round 3
// baseline (20951.562 us; speedup 1.0000x reference)
//
#include <hip/hip_runtime.h>

#define BB 512
#define TT 128
#define EE 512
#define HH 256
#define VV 39
#define H3 768
#define H2 512
#define TM1 127
#define NEGF (-3.402823466e38f)
#define NBLK 256

typedef unsigned short u16;
typedef unsigned int u32;
typedef __attribute__((ext_vector_type(8))) short s16x8;
typedef __attribute__((ext_vector_type(4))) float f32x4;

__device__ __forceinline__ float b2f(u16 u){ u32 x=((u32)u)<<16; return __uint_as_float(x); }
__device__ __forceinline__ u16 f2b(float f){ u32 x=__float_as_uint(f); u32 r=(x+0x7fffu+((x>>16)&1u))>>16; return (u16)r; }
__device__ __forceinline__ float sigm(float x){ return 1.f/(1.f+__expf(-x)); }
__device__ __forceinline__ float tanh1(float x){ float t=__expf(2.f*x); return 1.f-2.f/(t+1.f); }

// Device-scope grid barrier: monotone counter, target = phase*NBLK.
__device__ __forceinline__ void gbar(u32* cnt, u32 tgt){
  __syncthreads();
  if (threadIdx.x==0){
    __hip_atomic_fetch_add(cnt, 1u, __ATOMIC_RELEASE, __HIP_MEMORY_SCOPE_AGENT);
    while (__hip_atomic_load(cnt, __ATOMIC_RELAXED, __HIP_MEMORY_SCOPE_AGENT) < tgt)
      __builtin_amdgcn_s_sleep(2);
    __threadfence();
  }
  __syncthreads();
}

// ---------------------------------------------------------------------------
// Per-token input-projection tables (V=39).
__global__ __launch_bounds__(256) void k_tables(
    const float* __restrict__ src_emb, const float* __restrict__ trg_emb,
    const float* __restrict__ Wih_f, const float* __restrict__ bih_f,
    const float* __restrict__ Wih_b, const float* __restrict__ bih_b,
    const float* __restrict__ dec_Wih, const float* __restrict__ dec_bih,
    const float* __restrict__ pre_W,
    float* __restrict__ tab_gi_f, float* __restrict__ tab_gi_b,
    float* __restrict__ tab_dec, float* __restrict__ tab_pre)
{
  int v = blockIdx.x;
  int y = blockIdx.y;
  int tid = threadIdx.x;
  if (y < 9){
    int seg = y/3, part = y%3;
    int n = part*256 + tid;
    const float* emb; const float* W; const float* bias; float* out; int ldw;
    if (seg==0){ emb=src_emb; W=Wih_f; bias=bih_f; out=tab_gi_f; ldw=EE; }
    else if (seg==1){ emb=src_emb; W=Wih_b; bias=bih_b; out=tab_gi_b; ldw=EE; }
    else { emb=trg_emb; W=dec_Wih; bias=dec_bih; out=tab_dec; ldw=EE+H2; }
    float acc = bias[n];
    const float* er = emb + (size_t)v*EE;
    const float* wr = W + (size_t)n*ldw;
    for (int k=0;k<EE;k++) acc += er[k]*wr[k];
    out[(size_t)v*H3 + n] = acc;
  } else {
    int n = tid;
    float acc = 0.f;
    const float* er = trg_emb + (size_t)v*EE;
    const float* wr = pre_W + (size_t)n*1280;
    for (int k=0;k<EE;k++) acc += er[k]*wr[k];
    tab_pre[(size_t)v*HH + n] = acc;
  }
}

// All fp32->bf16 weight conversions in one kernel. grid(5376).
__global__ __launch_bounds__(256) void k_cvt_all(
    const float* __restrict__ eWhh_f, const float* __restrict__ eWhh_b,
    const float* __restrict__ dWhh, const float* __restrict__ dWih,
    const float* __restrict__ preW, const float* __restrict__ Wk,
    const float* __restrict__ Wq,
    u16* __restrict__ o1, u16* __restrict__ o2, u16* __restrict__ o3,
    u16* __restrict__ o4, u16* __restrict__ o5, u16* __restrict__ o6,
    u16* __restrict__ o7)
{
  int idx = blockIdx.x*256 + threadIdx.x;
  const float* src; u16* dst; int cols, ld, off, rel;
  if      (idx <  196608){ rel=idx;          src=eWhh_f; dst=o1; cols=256; ld=256;  off=0;   }
  else if (idx <  393216){ rel=idx-196608;   src=eWhh_b; dst=o2; cols=256; ld=256;  off=0;   }
  else if (idx <  589824){ rel=idx-393216;   src=dWhh;   dst=o3; cols=256; ld=256;  off=0;   }
  else if (idx <  983040){ rel=idx-589824;   src=dWih;   dst=o4; cols=512; ld=1024; off=512; }
  else if (idx < 1179648){ rel=idx-983040;   src=preW;   dst=o5; cols=768; ld=1280; off=512; }
  else if (idx < 1310720){ rel=idx-1179648;  src=Wk;     dst=o6; cols=512; ld=512;  off=0;   }
  else if (idx < 1376256){ rel=idx-1310720;  src=Wq;     dst=o7; cols=256; ld=256;  off=0;   }
  else return;
  int r = rel/cols, c2 = rel - r*cols;
  dst[rel] = f2b(src[(size_t)r*ld + off + c2]);
}

// ---------------------------------------------------------------------------
// WHOLE encoder in one kernel, zero grid barriers. grid(32): bx = dir*16 + mt
// (mt: 32-row tile). block 512 (8 waves). gh in LDS, h in registers.
__global__ __launch_bounds__(512) void k_enc_all(const int* __restrict__ input,
    const u16* __restrict__ wb_f, const u16* __restrict__ wb_b,
    const float* __restrict__ bhh_f, const float* __restrict__ bhh_b,
    const float* __restrict__ tab_f, const float* __restrict__ tab_b,
    float* __restrict__ h_f, float* __restrict__ h_b, u16* __restrict__ enc_out)
{
  __shared__ float gh[32][772];   // 98.8 KB: gh[row][0:768] for own 32 rows
  __shared__ u16 hs[32][264];     // 16.9 KB: h (bf16), K-contiguous
  int bx = blockIdx.x;
  int dirb = bx>>4, mt = bx&15;
  int m0 = mt*32;
  int tid = threadIdx.x;
  const float* tab = dirb? tab_b : tab_f;
  const float* bhh = dirb? bhh_b : bhh_f;
  const u16* Wb = dirb? wb_b : wb_f;
  int c = tid & 255, rh = tid>>8;            // gate lane: col c, row-half rh
  float b_r=bhh[c], b_z=bhh[c+256], b_n=bhh[c+512];
  float hreg[16];
  #pragma unroll
  for (int r=0;r<16;r++) hreg[r]=0.f;
  int wv = tid>>6, lane = tid&63, l15 = lane&15, kg=(lane>>4)*8;
  int n0w = wv*96;                            // wave's 6 col-tiles
  float* hOut = dirb? h_b : h_f;

  for (int s=1; s<=TT; s++){
    int tcol = dirb? (TT-s) : (s-1);
    // Phase A: gates -> h_s (regs + LDS bf16 + enc_out)
    #pragma unroll
    for (int r=0;r<16;r++){
      int row = rh*16 + r;
      int b = m0 + row;
      int tok = input[b*TT + tcol];
      const float* tg = tab + (size_t)tok*H3;
      float g0=0.f, g1=0.f, g2=0.f;
      if (s>1){ g0=gh[row][c]; g1=gh[row][c+256]; g2=gh[row][c+512]; }
      float rg = sigm(tg[c]     + g0 + b_r);
      float zg = sigm(tg[c+256] + g1 + b_z);
      float ng = tanh1(tg[c+512] + rg*(g2 + b_n));
      float hv = (1.f-zg)*ng + zg*hreg[r];
      hreg[r] = hv;
      u16 hb = f2b(hv);
      hs[row][c] = hb;
      enc_out[((size_t)b*TT + tcol)*H2 + (size_t)dirb*HH + c] = hb;
    }
    if (s==TT){
      #pragma unroll
      for (int r=0;r<16;r++)
        hOut[(size_t)(m0+rh*16+r)*HH + c] = hreg[r];
      break;
    }
    __syncthreads();
    // Phase B: gh = h_s @ Whh^T  (M=32, N=768, K=256) -> LDS
    f32x4 acc[2][6];
    #pragma unroll
    for (int rt=0;rt<2;rt++)
      #pragma unroll
      for (int nt=0;nt<6;nt++) acc[rt][nt]=(f32x4){0.f,0.f,0.f,0.f};
    const u16* ar0 = &hs[l15][0];
    const u16* ar1 = &hs[16+l15][0];
    for (int ko=0;ko<256;ko+=32){
      s16x8 a0 = *(const s16x8*)(ar0 + ko + kg);
      s16x8 a1 = *(const s16x8*)(ar1 + ko + kg);
      #pragma unroll
      for (int nt=0;nt<6;nt++){
        s16x8 bf = *(const s16x8*)(Wb + (size_t)(n0w+nt*16+l15)*HH + ko + kg);
        acc[0][nt] = __builtin_amdgcn_mfma_f32_16x16x32_bf16(a0, bf, acc[0][nt], 0,0,0);
        acc[1][nt] = __builtin_amdgcn_mfma_f32_16x16x32_bf16(a1, bf, acc[1][nt], 0,0,0);
      }
    }
    int q4 = (lane>>4)*4;
    #pragma unroll
    for (int rt=0;rt<2;rt++)
      #pragma unroll
      for (int nt=0;nt<6;nt++){
        int col = n0w + nt*16 + l15;
        #pragma unroll
        for (int j=0;j<4;j++)
          gh[rt*16 + q4 + j][col] = acc[rt][nt][j];
      }
    __syncthreads();
  }
}

// proj_key = enc_out @ Wk^T : M=65536, N=256, K=512, MFMA. grid(1024), block 256.
__global__ __launch_bounds__(256) void k_pk(const u16* __restrict__ enc_out,
    const u16* __restrict__ wbk, u16* __restrict__ pk)
{
  int m0 = blockIdx.x*64;
  int tid = threadIdx.x, wv = tid>>6, lane = tid&63;
  int l15 = lane&15, kg = (lane>>4)*8;
  int n0 = wv*64;
  f32x4 acc[4][4];
  #pragma unroll
  for (int rt=0;rt<4;rt++)
    #pragma unroll
    for (int nt=0;nt<4;nt++) acc[rt][nt] = (f32x4){0.f,0.f,0.f,0.f};
  for (int ko=0; ko<512; ko+=32){
    s16x8 a[4], b[4];
    #pragma unroll
    for (int rt=0;rt<4;rt++) a[rt] = *(const s16x8*)(enc_out + (size_t)(m0+rt*16+l15)*H2 + ko + kg);
    #pragma unroll
    for (int nt=0;nt<4;nt++) b[nt] = *(const s16x8*)(wbk + (size_t)(n0+nt*16+l15)*H2 + ko + kg);
    #pragma unroll
    for (int rt=0;rt<4;rt++)
      #pragma unroll
      for (int nt=0;nt<4;nt++)
        acc[rt][nt] = __builtin_amdgcn_mfma_f32_16x16x32_bf16(a[rt], b[nt], acc[rt][nt], 0,0,0);
  }
  #pragma unroll
  for (int rt=0;rt<4;rt++){
    int rbase = m0 + rt*16 + (lane>>4)*4;
    #pragma unroll
    for (int nt=0;nt<4;nt++){
      int col = n0 + nt*16 + l15;
      #pragma unroll
      for (int j=0;j<4;j++)
        pk[(size_t)(rbase+j)*HH + col] = f2b(acc[rt][nt][j]);
    }
  }
}

// hidden = tanh([h_f|h_b] @ bridge_W^T + b). fp32 one-time. grid (4,8).
__global__ __launch_bounds__(256) void k_bridge(const float* __restrict__ h_f,
    const float* __restrict__ h_b, const float* __restrict__ bw,
    const float* __restrict__ bb, float* __restrict__ hd)
{
  __shared__ float As[32][68];
  __shared__ float Ws[32][68];
  int n0=blockIdx.x*64, m0=blockIdx.y*64, tid=threadIdx.x;
  int ar=tid>>2, ak=(tid&3)*8;
  int rt=tid>>4, ct=tid&15;
  float acc[4][4];
  #pragma unroll
  for (int j=0;j<4;j++){
    #pragma unroll
    for (int l=0;l<4;l++) acc[j][l]=0.f;
  }
  for (int ko=0;ko<512;ko+=32){
    int k0=ko+ak;
    const float* asrc = (k0<256)? (h_f + (size_t)(m0+ar)*HH + k0)
                                : (h_b + (size_t)(m0+ar)*HH + (k0-256));
    float4 a0=*(const float4*)asrc, a1=*(const float4*)(asrc+4);
    const float* wsrc = bw + (size_t)(n0+ar)*H2 + k0;
    float4 w0=*(const float4*)wsrc, w1=*(const float4*)(wsrc+4);
    __syncthreads();
    As[ak+0][ar]=a0.x; As[ak+1][ar]=a0.y; As[ak+2][ar]=a0.z; As[ak+3][ar]=a0.w;
    As[ak+4][ar]=a1.x; As[ak+5][ar]=a1.y; As[ak+6][ar]=a1.z; As[ak+7][ar]=a1.w;
    Ws[ak+0][ar]=w0.x; Ws[ak+1][ar]=w0.y; Ws[ak+2][ar]=w0.z; Ws[ak+3][ar]=w0.w;
    Ws[ak+4][ar]=w1.x; Ws[ak+5][ar]=w1.y; Ws[ak+6][ar]=w1.z; Ws[ak+7][ar]=w1.w;
    __syncthreads();
    #pragma unroll
    for (int kk=0;kk<32;kk++){
      float4 a=*(const float4*)&As[kk][rt*4];
      float4 w=*(const float4*)&Ws[kk][ct*4];
      float a4[4]={a.x,a.y,a.z,a.w};
      float w4[4]={w.x,w.y,w.z,w.w};
      #pragma unroll
      for (int j=0;j<4;j++){
        #pragma unroll
        for (int l=0;l<4;l++) acc[j][l]+=a4[j]*w4[l];
      }
    }
  }
  #pragma unroll
  for (int j=0;j<4;j++){
    int row=m0+rt*4+j;
    #pragma unroll
    for (int l=0;l<4;l++){
      int col=n0+ct*4+l;
      hd[(size_t)row*HH+col]=tanh1(acc[j][l]+bb[col]);
    }
  }
}

// ---------------------------------------------------------------------------
// Decoder phase helpers (device functions used by the persistent kernel)

__device__ __forceinline__ void attn_nll_row(int i, int b, int do_attn, int tid,
    const int* __restrict__ input, const float* __restrict__ q,
    const u16* __restrict__ pk, const u16* __restrict__ enc_out,
    const float* __restrict__ We, const float* __restrict__ genW,
    const float* __restrict__ tab_pre, const float* __restrict__ pre_b,
    u16* __restrict__ ctx_bf, float* __restrict__ nll,
    float* se, float* sa, float* spre, int* stok, float* redm, float* reds)
{
  int lane = tid & 63;
  int w = tid >> 6;
  int do_nll = (i >= 2);
  __syncthreads();
  if (do_attn && tid < 128) stok[tid] = input[b*TT + tid];
  if (do_nll){
    int tokp = input[b*TT + (i-2)];
    const float* pp = pre_b + (size_t)(i&1)*BB*HH;   // parity (i-2)&1 == i&1
    spre[tid] = tab_pre[(size_t)tokp*HH + tid] + pp[(size_t)b*HH + tid];
  }
  __syncthreads();
  if (do_nll && w==0){
    float lg = NEGF;
    if (lane < VV){
      float s=0.f;
      const float* gw = genW + (size_t)lane*HH;
      for (int d=0; d<HH; d++) s += spre[d]*gw[d];
      lg = s;
    }
    float m = lg;
    #pragma unroll
    for (int off=32; off; off>>=1) m = fmaxf(m, __shfl_xor(m, off));
    float pe = (lane<VV)? __expf(lg - m) : 0.f;
    float ssum = pe;
    #pragma unroll
    for (int off=32; off; off>>=1) ssum += __shfl_xor(ssum, off);
    int ty = input[b*TT + (i-1)];
    float lty = __shfl(lg, ty);
    if (lane==0){
      float val = (ty != 0) ? (m + __logf(ssum) - lty) : 0.f;
      nll[(size_t)(i-2)*BB + b] = val;
    }
  }
  if (do_attn){
    float4 qv = *(const float4*)(q + (size_t)b*HH + lane*4);
    float4 wv = *(const float4*)(We + lane*4);
    const u16* pkb = pk + (size_t)b*TT*HH;
    for (int it=0; it<32; it++){
      int t = w*32 + it;
      ushort4 kv = *(const ushort4*)(pkb + (size_t)t*HH + lane*4);
      float s = tanh1(qv.x + b2f(kv.x))*wv.x + tanh1(qv.y + b2f(kv.y))*wv.y
              + tanh1(qv.z + b2f(kv.z))*wv.z + tanh1(qv.w + b2f(kv.w))*wv.w;
      #pragma unroll
      for (int off=32; off; off>>=1) s += __shfl_xor(s, off);
      if (lane==0) se[t] = (stok[t] != 0) ? s : NEGF;
    }
    __syncthreads();
    float v = (tid<128)? se[tid] : NEGF;
    float mm = v;
    #pragma unroll
    for (int off=32; off; off>>=1) mm = fmaxf(mm, __shfl_xor(mm, off));
    if (lane==0) redm[w]=mm;
    __syncthreads();
    float M = fmaxf(fmaxf(redm[0],redm[1]), fmaxf(redm[2],redm[3]));
    float pv = (tid<128)? __expf(v - M) : 0.f;
    float ps = pv;
    #pragma unroll
    for (int off=32; off; off>>=1) ps += __shfl_xor(ps, off);
    if (lane==0) reds[w]=ps;
    __syncthreads();
    float S = reds[0]+reds[1]+reds[2]+reds[3];
    if (tid<128) sa[tid] = pv/S;
    __syncthreads();
    const u16* eb = enc_out + (size_t)b*TT*H2;
    float c0=0.f, c1=0.f;
    for (int t=0;t<TT;t++){
      float a = sa[t];
      c0 += a*b2f(eb[(size_t)t*H2 + tid]);
      c1 += a*b2f(eb[(size_t)t*H2 + 256 + tid]);
    }
    u16* cb = ctx_bf + (size_t)(i&1)*BB*H2 + (size_t)b*H2;
    cb[tid] = f2b(c0);
    cb[tid+256] = f2b(c1);
  }
}

__device__ __forceinline__ void dec_gemm_job(int i, int x, int mt, int tid,
    const u16* __restrict__ hd_bf, const u16* __restrict__ ctx_bf,
    const u16* __restrict__ wb_dhh, const u16* __restrict__ wb_dih,
    const u16* __restrict__ wb_pre,
    float* __restrict__ gh_dec, float* __restrict__ gi_dec, float* __restrict__ pre_b)
{
  int m0 = mt*64;
  int wv=tid>>6, lane=tid&63;
  int l15=lane&15, kg=(lane>>4)*8;
  int mrow = m0 + wv*16;
  const u16* ctxC = ctx_bf + (size_t)(i&1)*BB*H2;
  const u16* ctxP = ctx_bf + (size_t)((i-1)&1)*BB*H2;
  const u16* aBase; int lda; const u16* wBase; int ldw; int K; int n0;
  float* optr; int ldo; int pre = 0;
  if (x < 12){       aBase=hd_bf; lda=HH; wBase=wb_dhh; ldw=HH; K=256; n0=x*64;
                     optr=gh_dec + (size_t)(i&1)*BB*H3; ldo=H3; }
  else if (x < 24){  aBase=ctxC;  lda=H2; wBase=wb_dih; ldw=H2; K=512; n0=(x-12)*64;
                     optr=gi_dec + (size_t)(i&1)*BB*H3; ldo=H3; }
  else {             aBase=hd_bf; lda=HH; wBase=wb_pre; ldw=H3; K=768; n0=(x-24)*64;
                     optr=pre_b + (size_t)((i-1)&1)*BB*HH; ldo=HH; pre=1; }
  f32x4 acc[4];
  #pragma unroll
  for (int nt=0;nt<4;nt++) acc[nt]=(f32x4){0.f,0.f,0.f,0.f};
  for (int ko=0; ko<K; ko+=32){
    const u16* ap;
    if (pre)
      ap = (ko<256) ? (hd_bf + (size_t)(mrow+l15)*HH + ko)
                    : (ctxP + (size_t)(mrow+l15)*H2 + (ko-256));
    else
      ap = aBase + (size_t)(mrow+l15)*lda + ko;
    s16x8 af = *(const s16x8*)(ap + kg);
    #pragma unroll
    for (int nt=0;nt<4;nt++){
      s16x8 bf = *(const s16x8*)(wBase + (size_t)(n0+nt*16+l15)*ldw + ko + kg);
      acc[nt] = __builtin_amdgcn_mfma_f32_16x16x32_bf16(af, bf, acc[nt], 0,0,0);
    }
  }
  int rb = mrow + (lane>>4)*4;
  #pragma unroll
  for (int nt=0;nt<4;nt++){
    int col = n0 + nt*16 + l15;
    #pragma unroll
    for (int j=0;j<4;j++)
      optr[(size_t)(rb+j)*ldo + col] = acc[nt][j];
  }
}

// ---------------------------------------------------------------------------
// WHOLE decoder in one persistent kernel. grid(256) x 256 (all co-resident).
__global__ __launch_bounds__(256) void k_dec_all(
    const int* __restrict__ input,
    const u16* __restrict__ wbq, const u16* __restrict__ wb_dhh,
    const u16* __restrict__ wb_dih, const u16* __restrict__ wb_pre,
    const float* __restrict__ tab_dec, const float* __restrict__ tab_pre,
    const float* __restrict__ bhh,
    const float* __restrict__ We, const float* __restrict__ genW,
    const u16* __restrict__ pk, const u16* __restrict__ enc_out,
    float* __restrict__ hd, u16* __restrict__ hd_bf, float* __restrict__ q,
    u16* __restrict__ ctx_bf, float* __restrict__ gh_dec, float* __restrict__ gi_dec,
    float* __restrict__ pre_b, float* __restrict__ nll, float* __restrict__ outp,
    u32* __restrict__ bar)
{
  __shared__ u16 hs[16][264];
  __shared__ float se[128], sa[128], spre[256];
  __shared__ int stok[128];
  __shared__ float redm[4], reds[4];
  int bx = blockIdx.x, tid = threadIdx.x;
  u32 phase = 0;

  for (int i=0;;i++){
    // ---- P1: gates (h_i) + q_i (blocks 0..31, 16 rows each)
    if (bx < 32){
      int m0 = bx*16, c = tid;
      if (i == 0){
        for (int r=0;r<16;r++){
          float hv = hd[(size_t)(m0+r)*HH + c];      // bridge output (parity 0)
          u16 hb = f2b(hv);
          hs[r][c] = hb;
          hd_bf[(size_t)(m0+r)*HH + c] = hb;
        }
      } else {
        int p = (i-1)&1;
        const float* ghR = gh_dec + (size_t)p*BB*H3;
        const float* giR = gi_dec + (size_t)p*BB*H3;
        const float* hR  = hd + (size_t)p*BB*HH;
        float* hdW = hd + (size_t)(i&1)*BB*HH;
        float b_r=bhh[c], b_z=bhh[c+256], b_n=bhh[c+512];
        for (int r=0;r<16;r++){
          int b = m0+r;
          int tok = input[b*TT + (i-1)];
          const float* tg = tab_dec + (size_t)tok*H3;
          const float* gr = ghR + (size_t)b*H3;
          const float* gi = giR + (size_t)b*H3;
          float rg = sigm(tg[c]     + gi[c]     + gr[c]     + b_r);
          float zg = sigm(tg[c+256] + gi[c+256] + gr[c+256] + b_z);
          float ng = tanh1(tg[c+512] + gi[c+512] + rg*(gr[c+512] + b_n));
          float hv = (1.f-zg)*ng + zg*hR[b*HH + c];
          u16 hb = f2b(hv);
          hs[r][c] = hb;
          hdW[b*HH + c] = hv;
          hd_bf[b*HH + c] = hb;
        }
      }
      __syncthreads();
      if (i < TM1){
        int wv=tid>>6, lane=tid&63, l15=lane&15, kg=(lane>>4)*8;
        int n0 = wv*64;
        f32x4 acc[4];
        #pragma unroll
        for (int nt=0;nt<4;nt++) acc[nt]=(f32x4){0.f,0.f,0.f,0.f};
        const u16* arow = &hs[l15][0];
        for (int ko=0;ko<256;ko+=32){
          s16x8 af = *(const s16x8*)(arow + ko + kg);
          #pragma unroll
          for (int nt=0;nt<4;nt++){
            s16x8 bf = *(const s16x8*)(wbq + (size_t)(n0+nt*16+l15)*HH + ko + kg);
            acc[nt] = __builtin_amdgcn_mfma_f32_16x16x32_bf16(af, bf, acc[nt], 0,0,0);
          }
        }
        int rb = m0 + (lane>>4)*4;
        #pragma unroll
        for (int nt=0;nt<4;nt++){
          int col = n0 + nt*16 + l15;
          #pragma unroll
          for (int j=0;j<4;j++)
            q[(size_t)(rb+j)*HH + col] = acc[nt][j];
        }
      }
    }
    gbar(bar, (++phase)*NBLK);
    if (i == TM1) break;

    // ---- P2: attention + nll(i-2); rows 2*bx, 2*bx+1
    for (int r=0;r<2;r++)
      attn_nll_row(i, bx*2+r, 1, tid, input, q, pk, enc_out, We, genW,
                   tab_pre, pre_b, ctx_bf, nll, se, sa, spre, stok, redm, reds);
    gbar(bar, (++phase)*NBLK);

    // ---- P3: GEMMs gh_i / gi_i / pre_{i-1} (224 jobs)
    if (bx < 224){
      int x = bx>>3, mtl = bx&7;
      if (!(i==0 && x>=24))
        dec_gemm_job(i, x, mtl, tid, hd_bf, ctx_bf, wb_dhh, wb_dih, wb_pre,
                     gh_dec, gi_dec, pre_b);
    }
    gbar(bar, (++phase)*NBLK);
  }

  // tail: pre_126 (needs h_127), 32 jobs
  if (bx < 32){
    int x = 24 + (bx>>3), mtl = bx&7;
    dec_gemm_job(TM1, x, mtl, tid, hd_bf, ctx_bf, wb_dhh, wb_dih, wb_pre,
                 gh_dec, gi_dec, pre_b);
  }
  gbar(bar, (++phase)*NBLK);
  // nll_125 (ii=127), nll_126 (ii=128)
  for (int ii=TM1; ii<=TT; ii++)
    for (int r=0;r<2;r++)
      attn_nll_row(ii, bx*2+r, 0, tid, input, q, pk, enc_out, We, genW,
                   tab_pre, pre_b, ctx_bf, nll, se, sa, spre, stok, redm, reds);
  gbar(bar, (++phase)*NBLK);
  // loss reduce
  if (bx == 0){
    float s=0.f;
    for (int idx=tid; idx<TM1*BB; idx+=256) s += nll[idx];
    spre[tid]=s; __syncthreads();
    for (int off=128; off; off>>=1){
      if (tid<off) spre[tid]+=spre[tid+off];
      __syncthreads();
    }
    if (tid==0) outp[0]=spre[0];
  }
}

extern "C" void kernel_launch(void* const* d_in, const int* in_sizes, int n_in,
                              void* d_out, int out_size, void* d_ws, size_t ws_size,
                              hipStream_t stream)
{
  const int*   input    = (const int*)  d_in[0];
  const float* src_emb  = (const float*)d_in[1];
  const float* trg_emb  = (const float*)d_in[2];
  const float* eWih_f   = (const float*)d_in[3];
  const float* eWhh_f   = (const float*)d_in[4];
  const float* ebih_f   = (const float*)d_in[5];
  const float* ebhh_f   = (const float*)d_in[6];
  const float* eWih_b   = (const float*)d_in[7];
  const float* eWhh_b   = (const float*)d_in[8];
  const float* ebih_b   = (const float*)d_in[9];
  const float* ebhh_b   = (const float*)d_in[10];
  const float* bridge_W = (const float*)d_in[11];
  const float* bridge_b = (const float*)d_in[12];
  const float* attn_Wk  = (const float*)d_in[13];
  const float* attn_Wq  = (const float*)d_in[14];
  const float* attn_We  = (const float*)d_in[15];
  const float* dec_Wih  = (const float*)d_in[16];
  const float* dec_Whh  = (const float*)d_in[17];
  const float* dec_bih  = (const float*)d_in[18];
  const float* dec_bhh  = (const float*)d_in[19];
  const float* pre_W    = (const float*)d_in[20];
  const float* gen_W    = (const float*)d_in[21];

  float* F = (float*)d_ws;
  size_t o=0;
  u32* bar        = (u32*)(F+o); o+=16;
  float* tab_gi_f = F+o; o+=(size_t)VV*H3;
  float* tab_gi_b = F+o; o+=(size_t)VV*H3;
  float* tab_dec  = F+o; o+=(size_t)VV*H3;
  float* tab_pre  = F+o; o+=(size_t)VV*HH;
  float* h_f      = F+o; o+=(size_t)BB*HH;
  float* h_b      = F+o; o+=(size_t)BB*HH;
  float* hd       = F+o; o+=(size_t)2*BB*HH;
  float* qb       = F+o; o+=(size_t)BB*HH;
  float* gh_dec   = F+o; o+=(size_t)2*BB*H3;
  float* gi_dec   = F+o; o+=(size_t)2*BB*H3;
  float* pre_b    = F+o; o+=(size_t)2*BB*HH;
  float* nll      = F+o; o+=(size_t)TM1*BB;
  u16* U = (u16*)(F+o);
  size_t uo=0;
  u16* enc_out = U+uo; uo+=(size_t)BB*TT*H2;
  u16* pk      = U+uo; uo+=(size_t)BB*TT*HH;
  u16* hd_bf   = U+uo; uo+=(size_t)BB*HH;
  u16* ctx_bf  = U+uo; uo+=(size_t)2*BB*H2;
  u16* wb_ehh_f= U+uo; uo+=(size_t)H3*HH;
  u16* wb_ehh_b= U+uo; uo+=(size_t)H3*HH;
  u16* wb_dhh  = U+uo; uo+=(size_t)H3*HH;
  u16* wb_dih  = U+uo; uo+=(size_t)H3*H2;
  u16* wb_pre  = U+uo; uo+=(size_t)HH*H3;
  u16* wb_wk   = U+uo; uo+=(size_t)HH*H2;
  u16* wb_wq   = U+uo; uo+=(size_t)HH*HH;

  dim3 blk(256,1,1);
  k_tables<<<dim3(VV,10),blk,0,stream>>>(src_emb,trg_emb,eWih_f,ebih_f,eWih_b,ebih_b,
                                         dec_Wih,dec_bih,pre_W,
                                         tab_gi_f,tab_gi_b,tab_dec,tab_pre);
  k_cvt_all<<<dim3(5376),blk,0,stream>>>(eWhh_f,eWhh_b,dec_Whh,dec_Wih,pre_W,attn_Wk,attn_Wq,
                                         wb_ehh_f,wb_ehh_b,wb_dhh,wb_dih,wb_pre,wb_wk,wb_wq);
  k_enc_all<<<dim3(32),dim3(512),0,stream>>>(input,wb_ehh_f,wb_ehh_b,ebhh_f,ebhh_b,
                                             tab_gi_f,tab_gi_b,h_f,h_b,enc_out);
  k_pk<<<dim3(1024),blk,0,stream>>>(enc_out,wb_wk,pk);
  k_bridge<<<dim3(4,8),blk,0,stream>>>(h_f,h_b,bridge_W,bridge_b,hd);
  hipMemsetAsync(bar, 0, sizeof(u32), stream);
  k_dec_all<<<dim3(NBLK),blk,0,stream>>>(input,wb_wq,wb_dhh,wb_dih,wb_pre,
                                         tab_dec,tab_pre,dec_bhh,attn_We,gen_W,
                                         pk,enc_out,hd,hd_bf,qb,ctx_bf,
                                         gh_dec,gi_dec,pre_b,nll,(float*)d_out,bar);
}

// Round 4
// 20204.543 us; speedup vs baseline: 1.0370x; 1.0370x over previous
//
#include <hip/hip_runtime.h>

#define BB 512
#define TT 128
#define EE 512
#define HH 256
#define VV 39
#define H3 768
#define H2 512
#define TM1 127
#define NEGF (-3.402823466e38f)

typedef unsigned short u16;
typedef unsigned int u32;
typedef __attribute__((ext_vector_type(8))) short s16x8;
typedef __attribute__((ext_vector_type(4))) float f32x4;

__device__ __forceinline__ float b2f(u16 u){ u32 x=((u32)u)<<16; return __uint_as_float(x); }
__device__ __forceinline__ u16 f2b(float f){ u32 x=__float_as_uint(f); u32 r=(x+0x7fffu+((x>>16)&1u))>>16; return (u16)r; }
__device__ __forceinline__ float sigm(float x){ return 1.f/(1.f+__expf(-x)); }
__device__ __forceinline__ float tanh1(float x){ float t=__expf(2.f*x); return 1.f-2.f/(t+1.f); }

// ---------------------------------------------------------------------------
// Per-token input-projection tables (V=39).
__global__ __launch_bounds__(256) void k_tables(
    const float* __restrict__ src_emb, const float* __restrict__ trg_emb,
    const float* __restrict__ Wih_f, const float* __restrict__ bih_f,
    const float* __restrict__ Wih_b, const float* __restrict__ bih_b,
    const float* __restrict__ dec_Wih, const float* __restrict__ dec_bih,
    const float* __restrict__ pre_W,
    float* __restrict__ tab_gi_f, float* __restrict__ tab_gi_b,
    float* __restrict__ tab_dec, float* __restrict__ tab_pre)
{
  int v = blockIdx.x;
  int y = blockIdx.y;
  int tid = threadIdx.x;
  if (y < 9){
    int seg = y/3, part = y%3;
    int n = part*256 + tid;
    const float* emb; const float* W; const float* bias; float* out; int ldw;
    if (seg==0){ emb=src_emb; W=Wih_f; bias=bih_f; out=tab_gi_f; ldw=EE; }
    else if (seg==1){ emb=src_emb; W=Wih_b; bias=bih_b; out=tab_gi_b; ldw=EE; }
    else { emb=trg_emb; W=dec_Wih; bias=dec_bih; out=tab_dec; ldw=EE+H2; }
    float acc = bias[n];
    const float* er = emb + (size_t)v*EE;
    const float* wr = W + (size_t)n*ldw;
    for (int k=0;k<EE;k++) acc += er[k]*wr[k];
    out[(size_t)v*H3 + n] = acc;
  } else {
    int n = tid;
    float acc = 0.f;
    const float* er = trg_emb + (size_t)v*EE;
    const float* wr = pre_W + (size_t)n*1280;
    for (int k=0;k<EE;k++) acc += er[k]*wr[k];
    tab_pre[(size_t)v*HH + n] = acc;
  }
}

// All fp32->bf16 weight conversions (incl. genW padded to 48 rows). grid(5424).
__global__ __launch_bounds__(256) void k_cvt_all(
    const float* __restrict__ eWhh_f, const float* __restrict__ eWhh_b,
    const float* __restrict__ dWhh, const float* __restrict__ dWih,
    const float* __restrict__ preW, const float* __restrict__ Wk,
    const float* __restrict__ Wq, const float* __restrict__ genW,
    u16* __restrict__ o1, u16* __restrict__ o2, u16* __restrict__ o3,
    u16* __restrict__ o4, u16* __restrict__ o5, u16* __restrict__ o6,
    u16* __restrict__ o7, u16* __restrict__ o8)
{
  int idx = blockIdx.x*256 + threadIdx.x;
  const float* src; u16* dst; int cols, ld, off, rel;
  if      (idx <  196608){ rel=idx;          src=eWhh_f; dst=o1; cols=256; ld=256;  off=0;   }
  else if (idx <  393216){ rel=idx-196608;   src=eWhh_b; dst=o2; cols=256; ld=256;  off=0;   }
  else if (idx <  589824){ rel=idx-393216;   src=dWhh;   dst=o3; cols=256; ld=256;  off=0;   }
  else if (idx <  983040){ rel=idx-589824;   src=dWih;   dst=o4; cols=512; ld=1024; off=512; }
  else if (idx < 1179648){ rel=idx-983040;   src=preW;   dst=o5; cols=768; ld=1280; off=512; }
  else if (idx < 1310720){ rel=idx-1179648;  src=Wk;     dst=o6; cols=512; ld=512;  off=0;   }
  else if (idx < 1376256){ rel=idx-1310720;  src=Wq;     dst=o7; cols=256; ld=256;  off=0;   }
  else if (idx < 1388544){
    rel=idx-1376256; int r=rel>>8, c2=rel&255;
    o8[rel] = (r<VV)? f2b(genW[(size_t)r*HH + c2]) : (u16)0;
    return;
  }
  else return;
  int r = rel/cols, c2 = rel - r*cols;
  dst[rel] = f2b(src[(size_t)r*ld + off + c2]);
}

// ---------------------------------------------------------------------------
// WHOLE encoder in one kernel, zero grid barriers. grid(32): bx = dir*16 + mt
// (mt: 32-row tile). block 512 (8 waves). gh in LDS, h in registers.
__global__ __launch_bounds__(512) void k_enc_all(const int* __restrict__ input,
    const u16* __restrict__ wb_f, const u16* __restrict__ wb_b,
    const float* __restrict__ bhh_f, const float* __restrict__ bhh_b,
    const float* __restrict__ tab_f, const float* __restrict__ tab_b,
    float* __restrict__ h_f, float* __restrict__ h_b, u16* __restrict__ enc_out)
{
  __shared__ float gh[32][772];
  __shared__ u16 hs[32][264];
  int bx = blockIdx.x;
  int dirb = bx>>4, mt = bx&15;
  int m0 = mt*32;
  int tid = threadIdx.x;
  const float* tab = dirb? tab_b : tab_f;
  const float* bhh = dirb? bhh_b : bhh_f;
  const u16* Wb = dirb? wb_b : wb_f;
  int c = tid & 255, rh = tid>>8;
  float b_r=bhh[c], b_z=bhh[c+256], b_n=bhh[c+512];
  float hreg[16];
  #pragma unroll
  for (int r=0;r<16;r++) hreg[r]=0.f;
  int wv = tid>>6, lane = tid&63, l15 = lane&15, kg=(lane>>4)*8;
  int n0w = wv*96;
  float* hOut = dirb? h_b : h_f;

  for (int s=1; s<=TT; s++){
    int tcol = dirb? (TT-s) : (s-1);
    #pragma unroll
    for (int r=0;r<16;r++){
      int row = rh*16 + r;
      int b = m0 + row;
      int tok = input[b*TT + tcol];
      const float* tg = tab + (size_t)tok*H3;
      float g0=0.f, g1=0.f, g2=0.f;
      if (s>1){ g0=gh[row][c]; g1=gh[row][c+256]; g2=gh[row][c+512]; }
      float rg = sigm(tg[c]     + g0 + b_r);
      float zg = sigm(tg[c+256] + g1 + b_z);
      float ng = tanh1(tg[c+512] + rg*(g2 + b_n));
      float hv = (1.f-zg)*ng + zg*hreg[r];
      hreg[r] = hv;
      u16 hb = f2b(hv);
      hs[row][c] = hb;
      enc_out[((size_t)b*TT + tcol)*H2 + (size_t)dirb*HH + c] = hb;
    }
    if (s==TT){
      #pragma unroll
      for (int r=0;r<16;r++)
        hOut[(size_t)(m0+rh*16+r)*HH + c] = hreg[r];
      break;
    }
    __syncthreads();
    f32x4 acc[2][6];
    #pragma unroll
    for (int rt=0;rt<2;rt++)
      #pragma unroll
      for (int nt=0;nt<6;nt++) acc[rt][nt]=(f32x4){0.f,0.f,0.f,0.f};
    const u16* ar0 = &hs[l15][0];
    const u16* ar1 = &hs[16+l15][0];
    for (int ko=0;ko<256;ko+=32){
      s16x8 a0 = *(const s16x8*)(ar0 + ko + kg);
      s16x8 a1 = *(const s16x8*)(ar1 + ko + kg);
      #pragma unroll
      for (int nt=0;nt<6;nt++){
        s16x8 bf = *(const s16x8*)(Wb + (size_t)(n0w+nt*16+l15)*HH + ko + kg);
        acc[0][nt] = __builtin_amdgcn_mfma_f32_16x16x32_bf16(a0, bf, acc[0][nt], 0,0,0);
        acc[1][nt] = __builtin_amdgcn_mfma_f32_16x16x32_bf16(a1, bf, acc[1][nt], 0,0,0);
      }
    }
    int q4 = (lane>>4)*4;
    #pragma unroll
    for (int rt=0;rt<2;rt++)
      #pragma unroll
      for (int nt=0;nt<6;nt++){
        int col = n0w + nt*16 + l15;
        #pragma unroll
        for (int j=0;j<4;j++)
          gh[rt*16 + q4 + j][col] = acc[rt][nt][j];
      }
    __syncthreads();
  }
}

// proj_key = enc_out @ Wk^T : MFMA. grid(1024), block 256.
__global__ __launch_bounds__(256) void k_pk(const u16* __restrict__ enc_out,
    const u16* __restrict__ wbk, u16* __restrict__ pk)
{
  int m0 = blockIdx.x*64;
  int tid = threadIdx.x, wv = tid>>6, lane = tid&63;
  int l15 = lane&15, kg = (lane>>4)*8;
  int n0 = wv*64;
  f32x4 acc[4][4];
  #pragma unroll
  for (int rt=0;rt<4;rt++)
    #pragma unroll
    for (int nt=0;nt<4;nt++) acc[rt][nt] = (f32x4){0.f,0.f,0.f,0.f};
  for (int ko=0; ko<512; ko+=32){
    s16x8 a[4], b[4];
    #pragma unroll
    for (int rt=0;rt<4;rt++) a[rt] = *(const s16x8*)(enc_out + (size_t)(m0+rt*16+l15)*H2 + ko + kg);
    #pragma unroll
    for (int nt=0;nt<4;nt++) b[nt] = *(const s16x8*)(wbk + (size_t)(n0+nt*16+l15)*H2 + ko + kg);
    #pragma unroll
    for (int rt=0;rt<4;rt++)
      #pragma unroll
      for (int nt=0;nt<4;nt++)
        acc[rt][nt] = __builtin_amdgcn_mfma_f32_16x16x32_bf16(a[rt], b[nt], acc[rt][nt], 0,0,0);
  }
  #pragma unroll
  for (int rt=0;rt<4;rt++){
    int rbase = m0 + rt*16 + (lane>>4)*4;
    #pragma unroll
    for (int nt=0;nt<4;nt++){
      int col = n0 + nt*16 + l15;
      #pragma unroll
      for (int j=0;j<4;j++)
        pk[(size_t)(rbase+j)*HH + col] = f2b(acc[rt][nt][j]);
    }
  }
}

// hidden = tanh([h_f|h_b] @ bridge_W^T + b). fp32 one-time. grid (4,8).
__global__ __launch_bounds__(256) void k_bridge(const float* __restrict__ h_f,
    const float* __restrict__ h_b, const float* __restrict__ bw,
    const float* __restrict__ bb, float* __restrict__ hd)
{
  __shared__ float As[32][68];
  __shared__ float Ws[32][68];
  int n0=blockIdx.x*64, m0=blockIdx.y*64, tid=threadIdx.x;
  int ar=tid>>2, ak=(tid&3)*8;
  int rt=tid>>4, ct=tid&15;
  float acc[4][4];
  #pragma unroll
  for (int j=0;j<4;j++){
    #pragma unroll
    for (int l=0;l<4;l++) acc[j][l]=0.f;
  }
  for (int ko=0;ko<512;ko+=32){
    int k0=ko+ak;
    const float* asrc = (k0<256)? (h_f + (size_t)(m0+ar)*HH + k0)
                                : (h_b + (size_t)(m0+ar)*HH + (k0-256));
    float4 a0=*(const float4*)asrc, a1=*(const float4*)(asrc+4);
    const float* wsrc = bw + (size_t)(n0+ar)*H2 + k0;
    float4 w0=*(const float4*)wsrc, w1=*(const float4*)(wsrc+4);
    __syncthreads();
    As[ak+0][ar]=a0.x; As[ak+1][ar]=a0.y; As[ak+2][ar]=a0.z; As[ak+3][ar]=a0.w;
    As[ak+4][ar]=a1.x; As[ak+5][ar]=a1.y; As[ak+6][ar]=a1.z; As[ak+7][ar]=a1.w;
    Ws[ak+0][ar]=w0.x; Ws[ak+1][ar]=w0.y; Ws[ak+2][ar]=w0.z; Ws[ak+3][ar]=w0.w;
    Ws[ak+4][ar]=w1.x; Ws[ak+5][ar]=w1.y; Ws[ak+6][ar]=w1.z; Ws[ak+7][ar]=w1.w;
    __syncthreads();
    #pragma unroll
    for (int kk=0;kk<32;kk++){
      float4 a=*(const float4*)&As[kk][rt*4];
      float4 w=*(const float4*)&Ws[kk][ct*4];
      float a4[4]={a.x,a.y,a.z,a.w};
      float w4[4]={w.x,w.y,w.z,w.w};
      #pragma unroll
      for (int j=0;j<4;j++){
        #pragma unroll
        for (int l=0;l<4;l++) acc[j][l]+=a4[j]*w4[l];
      }
    }
  }
  #pragma unroll
  for (int j=0;j<4;j++){
    int row=m0+rt*4+j;
    #pragma unroll
    for (int l=0;l<4;l++){
      int col=n0+ct*4+l;
      hd[(size_t)row*HH+col]=tanh1(acc[j][l]+bb[col]);
    }
  }
}

// ---------------------------------------------------------------------------
// WHOLE decoder, row-persistent, zero grid barriers. grid(128): 4 rows/block.
// block 256 (4 waves). All state in LDS; weights streamed from L2.
__global__ __launch_bounds__(256) void k_dec_row(
    const int* __restrict__ input, const float* __restrict__ hd,
    const float* __restrict__ tab_dec, const float* __restrict__ tab_pre,
    const float* __restrict__ bhh, const float* __restrict__ We,
    const u16* __restrict__ wq, const u16* __restrict__ whh,
    const u16* __restrict__ wih, const u16* __restrict__ wpre,
    const u16* __restrict__ wgen,
    const u16* __restrict__ pk, const u16* __restrict__ enc_out,
    float* __restrict__ nll_part)
{
  __shared__ u16 h_bf[16][264];     // rows 4..15 stay zero (MFMA A pad)
  __shared__ u16 ctx_bf[16][520];
  __shared__ u16 pre_bf[16][264];
  __shared__ float h_f[4][256];
  __shared__ float qv[4][256];
  __shared__ float gh[4][768];
  __shared__ float gic[4][768];
  __shared__ float sa[4][128];
  __shared__ float lgt[4][48];
  __shared__ int   stok[4][128];
  __shared__ float nls[4];

  int bx = blockIdx.x, tid = threadIdx.x;
  int wv = tid>>6, lane = tid&63, l15 = lane&15, kg = (lane>>4)*8;
  int b0 = bx*4;

  // init: zero padded bf16 arrays, load tokens, h0 from bridge
  { u16* z = &h_bf[0][0];   for (int e=tid; e<16*264; e+=256) z[e]=0; }
  { u16* z = &ctx_bf[0][0]; for (int e=tid; e<16*520; e+=256) z[e]=0; }
  { u16* z = &pre_bf[0][0]; for (int e=tid; e<16*264; e+=256) z[e]=0; }
  for (int e=tid; e<4*128; e+=256){ int r=e>>7, t=e&127; stok[r][t]=input[(b0+r)*TT+t]; }
  {
    int c = tid;
    for (int r=0;r<4;r++){
      float v = hd[(size_t)(b0+r)*HH + c];
      h_f[r][c]=v; h_bf[r][c]=f2b(v);
    }
  }
  if (tid<4) nls[tid]=0.f;
  float4 wE = *(const float4*)(We + lane*4);
  float b_r=bhh[tid], b_z=bhh[tid+256], b_n=bhh[tid+512];
  __syncthreads();

  for (int j=0;j<TM1;j++){
    // ---- q = h @ Wq^T (N=256: 4 ntiles/wave)
    #pragma unroll
    for (int nt=0;nt<4;nt++){
      int n0 = wv*64 + nt*16;
      f32x4 acc = (f32x4){0.f,0.f,0.f,0.f};
      for (int ko=0;ko<256;ko+=32){
        s16x8 a = *(const s16x8*)&h_bf[l15][ko+kg];
        s16x8 bfr = *(const s16x8*)(wq + (size_t)(n0+l15)*HH + ko + kg);
        acc = __builtin_amdgcn_mfma_f32_16x16x32_bf16(a, bfr, acc, 0,0,0);
      }
      if (lane<16){
        #pragma unroll
        for (int jr=0;jr<4;jr++) qv[jr][n0+l15] = acc[jr];
      }
    }
    __syncthreads();

    // ---- attention: wave wv -> row wv
    {
      int r = wv, b = b0+r;
      float4 qq = *(const float4*)&qv[r][lane*4];
      const u16* pkb = pk + (size_t)b*TT*HH + lane*4;
      for (int t=0;t<TT;t+=2){
        ushort4 k0 = *(const ushort4*)(pkb + (size_t)t*HH);
        ushort4 k1 = *(const ushort4*)(pkb + (size_t)(t+1)*HH);
        float s0 = tanh1(qq.x+b2f(k0.x))*wE.x + tanh1(qq.y+b2f(k0.y))*wE.y
                 + tanh1(qq.z+b2f(k0.z))*wE.z + tanh1(qq.w+b2f(k0.w))*wE.w;
        float s1 = tanh1(qq.x+b2f(k1.x))*wE.x + tanh1(qq.y+b2f(k1.y))*wE.y
                 + tanh1(qq.z+b2f(k1.z))*wE.z + tanh1(qq.w+b2f(k1.w))*wE.w;
        #pragma unroll
        for (int off=32; off; off>>=1){ s0 += __shfl_xor(s0, off); s1 += __shfl_xor(s1, off); }
        if (lane==0){
          sa[r][t]   = stok[r][t]   ? s0 : NEGF;
          sa[r][t+1] = stok[r][t+1] ? s1 : NEGF;
        }
      }
      float v0 = sa[r][lane], v1 = sa[r][64+lane];
      float m = fmaxf(v0,v1);
      #pragma unroll
      for (int off=32; off; off>>=1) m = fmaxf(m, __shfl_xor(m, off));
      float p0 = __expf(v0-m), p1 = __expf(v1-m);
      float s = p0+p1;
      #pragma unroll
      for (int off=32; off; off>>=1) s += __shfl_xor(s, off);
      float inv = 1.f/s;
      sa[r][lane] = p0*inv; sa[r][64+lane] = p1*inv;
      // ctx: lane owns dims lane*8..lane*8+7
      float cacc[8];
      #pragma unroll
      for (int e=0;e<8;e++) cacc[e]=0.f;
      const u16* eb = enc_out + (size_t)b*TT*H2 + lane*8;
      for (int t=0;t<TT;t+=4){
        s16x8 v0_ = *(const s16x8*)(eb + (size_t)(t+0)*H2);
        s16x8 v1_ = *(const s16x8*)(eb + (size_t)(t+1)*H2);
        s16x8 v2_ = *(const s16x8*)(eb + (size_t)(t+2)*H2);
        s16x8 v3_ = *(const s16x8*)(eb + (size_t)(t+3)*H2);
        float a0=sa[r][t], a1=sa[r][t+1], a2=sa[r][t+2], a3=sa[r][t+3];
        #pragma unroll
        for (int e=0;e<8;e++)
          cacc[e] += a0*b2f((u16)v0_[e]) + a1*b2f((u16)v1_[e])
                   + a2*b2f((u16)v2_[e]) + a3*b2f((u16)v3_[e]);
      }
      #pragma unroll
      for (int e=0;e<8;e++) ctx_bf[r][lane*8+e] = f2b(cacc[e]);
    }
    __syncthreads();

    // ---- gh = h@Whh^T (K=256), gic = ctx@Wih_ctx^T (K=512); 12 ntiles/wave each
    #pragma unroll 2
    for (int nt=0;nt<12;nt++){
      int n0 = wv*192 + nt*16;
      f32x4 acc = (f32x4){0.f,0.f,0.f,0.f};
      for (int ko=0;ko<256;ko+=32){
        s16x8 a = *(const s16x8*)&h_bf[l15][ko+kg];
        s16x8 bfr = *(const s16x8*)(whh + (size_t)(n0+l15)*HH + ko + kg);
        acc = __builtin_amdgcn_mfma_f32_16x16x32_bf16(a, bfr, acc, 0,0,0);
      }
      if (lane<16){
        #pragma unroll
        for (int jr=0;jr<4;jr++) gh[jr][n0+l15] = acc[jr];
      }
      f32x4 acc2 = (f32x4){0.f,0.f,0.f,0.f};
      for (int ko=0;ko<512;ko+=32){
        s16x8 a = *(const s16x8*)&ctx_bf[l15][ko+kg];
        s16x8 bfr = *(const s16x8*)(wih + (size_t)(n0+l15)*H2 + ko + kg);
        acc2 = __builtin_amdgcn_mfma_f32_16x16x32_bf16(a, bfr, acc2, 0,0,0);
      }
      if (lane<16){
        #pragma unroll
        for (int jr=0;jr<4;jr++) gic[jr][n0+l15] = acc2[jr];
      }
    }
    __syncthreads();

    // ---- gates -> hn (thread = col, 4 rows)
    {
      int c = tid;
      #pragma unroll
      for (int r=0;r<4;r++){
        int tok = stok[r][j];
        const float* tg = tab_dec + (size_t)tok*H3;
        float rg = sigm(tg[c]     + gic[r][c]     + gh[r][c]     + b_r);
        float zg = sigm(tg[c+256] + gic[r][c+256] + gh[r][c+256] + b_z);
        float ng = tanh1(tg[c+512] + gic[r][c+512] + rg*(gh[r][c+512] + b_n));
        float hv = (1.f-zg)*ng + zg*h_f[r][c];
        h_f[r][c] = hv;
        h_bf[r][c] = f2b(hv);
      }
    }
    __syncthreads();

    // ---- pre = tab_pre[tok] + [hn|ctx] @ wpre^T (N=256, K=768)
    #pragma unroll
    for (int nt=0;nt<4;nt++){
      int n0 = wv*64 + nt*16;
      f32x4 acc = (f32x4){0.f,0.f,0.f,0.f};
      for (int ko=0;ko<768;ko+=32){
        s16x8 a = (ko<256) ? *(const s16x8*)&h_bf[l15][ko+kg]
                           : *(const s16x8*)&ctx_bf[l15][ko-256+kg];
        s16x8 bfr = *(const s16x8*)(wpre + (size_t)(n0+l15)*H3 + ko + kg);
        acc = __builtin_amdgcn_mfma_f32_16x16x32_bf16(a, bfr, acc, 0,0,0);
      }
      if (lane<16){
        #pragma unroll
        for (int jr=0;jr<4;jr++){
          int tok = stok[jr][j];
          float pv = acc[jr] + tab_pre[(size_t)tok*HH + n0 + l15];
          pre_bf[jr][n0+l15] = f2b(pv);
        }
      }
    }
    __syncthreads();

    // ---- logits = pre @ genW^T (N=48: waves 0..2)
    if (wv < 3){
      int n0 = wv*16;
      f32x4 acc = (f32x4){0.f,0.f,0.f,0.f};
      for (int ko=0;ko<256;ko+=32){
        s16x8 a = *(const s16x8*)&pre_bf[l15][ko+kg];
        s16x8 bfr = *(const s16x8*)(wgen + (size_t)(n0+l15)*HH + ko + kg);
        acc = __builtin_amdgcn_mfma_f32_16x16x32_bf16(a, bfr, acc, 0,0,0);
      }
      if (lane<16){
        #pragma unroll
        for (int jr=0;jr<4;jr++) lgt[jr][n0+l15] = acc[jr];
      }
    }
    __syncthreads();

    // ---- nll: wave wv -> row wv
    {
      int r = wv;
      float lg = (lane < VV)? lgt[r][lane] : NEGF;
      float m = lg;
      #pragma unroll
      for (int off=32; off; off>>=1) m = fmaxf(m, __shfl_xor(m, off));
      float pe = (lane < VV)? __expf(lg - m) : 0.f;
      float ss = pe;
      #pragma unroll
      for (int off=32; off; off>>=1) ss += __shfl_xor(ss, off);
      int ty = stok[r][j+1];
      float lty = __shfl(lg, ty);
      if (lane==0 && ty!=0) nls[r] += m + __logf(ss) - lty;
    }
    __syncthreads();
  }
  if (tid==0) nll_part[bx] = nls[0]+nls[1]+nls[2]+nls[3];
}

__global__ __launch_bounds__(256) void k_loss(const float* __restrict__ nll_part,
                                              float* __restrict__ out)
{
  __shared__ float sm[256];
  int tid=threadIdx.x;
  float s = (tid<128)? nll_part[tid] : 0.f;
  sm[tid]=s; __syncthreads();
  for (int off=128; off; off>>=1){
    if (tid<off) sm[tid]+=sm[tid+off];
    __syncthreads();
  }
  if (tid==0) out[0]=sm[0];
}

extern "C" void kernel_launch(void* const* d_in, const int* in_sizes, int n_in,
                              void* d_out, int out_size, void* d_ws, size_t ws_size,
                              hipStream_t stream)
{
  const int*   input    = (const int*)  d_in[0];
  const float* src_emb  = (const float*)d_in[1];
  const float* trg_emb  = (const float*)d_in[2];
  const float* eWih_f   = (const float*)d_in[3];
  const float* eWhh_f   = (const float*)d_in[4];
  const float* ebih_f   = (const float*)d_in[5];
  const float* ebhh_f   = (const float*)d_in[6];
  const float* eWih_b   = (const float*)d_in[7];
  const float* eWhh_b   = (const float*)d_in[8];
  const float* ebih_b   = (const float*)d_in[9];
  const float* ebhh_b   = (const float*)d_in[10];
  const float* bridge_W = (const float*)d_in[11];
  const float* bridge_b = (const float*)d_in[12];
  const float* attn_Wk  = (const float*)d_in[13];
  const float* attn_Wq  = (const float*)d_in[14];
  const float* attn_We  = (const float*)d_in[15];
  const float* dec_Wih  = (const float*)d_in[16];
  const float* dec_Whh  = (const float*)d_in[17];
  const float* dec_bih  = (const float*)d_in[18];
  const float* dec_bhh  = (const float*)d_in[19];
  const float* pre_W    = (const float*)d_in[20];
  const float* gen_W    = (const float*)d_in[21];

  float* F = (float*)d_ws;
  size_t o=0;
  float* tab_gi_f = F+o; o+=(size_t)VV*H3;
  float* tab_gi_b = F+o; o+=(size_t)VV*H3;
  float* tab_dec  = F+o; o+=(size_t)VV*H3;
  float* tab_pre  = F+o; o+=(size_t)VV*HH;
  float* h_f      = F+o; o+=(size_t)BB*HH;
  float* h_b      = F+o; o+=(size_t)BB*HH;
  float* hd       = F+o; o+=(size_t)BB*HH;
  float* nll_part = F+o; o+=(size_t)128;
  u16* U = (u16*)(F+o);
  size_t uo=0;
  u16* enc_out = U+uo; uo+=(size_t)BB*TT*H2;
  u16* pk      = U+uo; uo+=(size_t)BB*TT*HH;
  u16* wb_ehh_f= U+uo; uo+=(size_t)H3*HH;
  u16* wb_ehh_b= U+uo; uo+=(size_t)H3*HH;
  u16* wb_dhh  = U+uo; uo+=(size_t)H3*HH;
  u16* wb_dih  = U+uo; uo+=(size_t)H3*H2;
  u16* wb_pre  = U+uo; uo+=(size_t)HH*H3;
  u16* wb_wk   = U+uo; uo+=(size_t)HH*H2;
  u16* wb_wq   = U+uo; uo+=(size_t)HH*HH;
  u16* wb_gen  = U+uo; uo+=(size_t)48*HH;

  dim3 blk(256,1,1);
  k_tables<<<dim3(VV,10),blk,0,stream>>>(src_emb,trg_emb,eWih_f,ebih_f,eWih_b,ebih_b,
                                         dec_Wih,dec_bih,pre_W,
                                         tab_gi_f,tab_gi_b,tab_dec,tab_pre);
  k_cvt_all<<<dim3(5424),blk,0,stream>>>(eWhh_f,eWhh_b,dec_Whh,dec_Wih,pre_W,attn_Wk,attn_Wq,gen_W,
                                         wb_ehh_f,wb_ehh_b,wb_dhh,wb_dih,wb_pre,wb_wk,wb_wq,wb_gen);
  k_enc_all<<<dim3(32),dim3(512),0,stream>>>(input,wb_ehh_f,wb_ehh_b,ebhh_f,ebhh_b,
                                             tab_gi_f,tab_gi_b,h_f,h_b,enc_out);
  k_pk<<<dim3(1024),blk,0,stream>>>(enc_out,wb_wk,pk);
  k_bridge<<<dim3(4,8),blk,0,stream>>>(h_f,h_b,bridge_W,bridge_b,hd);
  k_dec_row<<<dim3(128),blk,0,stream>>>(input,hd,tab_dec,tab_pre,dec_bhh,attn_We,
                                        wb_wq,wb_dhh,wb_dih,wb_pre,wb_gen,
                                        pk,enc_out,nll_part);
  k_loss<<<dim3(1),blk,0,stream>>>(nll_part,(float*)d_out);
}

// Round 5
// 18370.164 us; speedup vs baseline: 1.1405x; 1.0999x over previous
//
#include <hip/hip_runtime.h>

#define BB 512
#define TT 128
#define EE 512
#define HH 256
#define VV 39
#define H3 768
#define H2 512
#define TM1 127
#define NEGF (-3.402823466e38f)

typedef unsigned short u16;
typedef unsigned int u32;
typedef __attribute__((ext_vector_type(8))) short s16x8;
typedef __attribute__((ext_vector_type(4))) float f32x4;

__device__ __forceinline__ float b2f(u16 u){ u32 x=((u32)u)<<16; return __uint_as_float(x); }
__device__ __forceinline__ u16 f2b(float f){ u32 x=__float_as_uint(f); u32 r=(x+0x7fffu+((x>>16)&1u))>>16; return (u16)r; }
__device__ __forceinline__ float sigm(float x){ return 1.f/(1.f+__expf(-x)); }
__device__ __forceinline__ float tanh1(float x){ float t=__expf(2.f*x); return 1.f-2.f/(t+1.f); }
__device__ __forceinline__ float bfl(u32 u){ return __uint_as_float(u<<16); }
__device__ __forceinline__ float bfh(u32 u){ return __uint_as_float(u & 0xffff0000u); }

// bf16-weight-row dot LDS-fp32 vector (broadcast reads). K multiple of 8.
__device__ __forceinline__ float dotw(const u16* __restrict__ wr,
                                      const float* __restrict__ xl, int K){
  float acc = 0.f;
  for (int k=0; k<K; k+=8){
    uint4 w = *(const uint4*)(wr+k);
    float4 x0 = *(const float4*)(xl+k);
    float4 x1 = *(const float4*)(xl+k+4);
    acc += bfl(w.x)*x0.x + bfh(w.x)*x0.y
         + bfl(w.y)*x0.z + bfh(w.y)*x0.w
         + bfl(w.z)*x1.x + bfh(w.z)*x1.y
         + bfl(w.w)*x1.z + bfh(w.w)*x1.w;
  }
  return acc;
}

// ---------------------------------------------------------------------------
// Per-token input-projection tables (V=39).
__global__ __launch_bounds__(256) void k_tables(
    const float* __restrict__ src_emb, const float* __restrict__ trg_emb,
    const float* __restrict__ Wih_f, const float* __restrict__ bih_f,
    const float* __restrict__ Wih_b, const float* __restrict__ bih_b,
    const float* __restrict__ dec_Wih, const float* __restrict__ dec_bih,
    const float* __restrict__ pre_W,
    float* __restrict__ tab_gi_f, float* __restrict__ tab_gi_b,
    float* __restrict__ tab_dec, float* __restrict__ tab_pre)
{
  int v = blockIdx.x;
  int y = blockIdx.y;
  int tid = threadIdx.x;
  if (y < 9){
    int seg = y/3, part = y%3;
    int n = part*256 + tid;
    const float* emb; const float* W; const float* bias; float* out; int ldw;
    if (seg==0){ emb=src_emb; W=Wih_f; bias=bih_f; out=tab_gi_f; ldw=EE; }
    else if (seg==1){ emb=src_emb; W=Wih_b; bias=bih_b; out=tab_gi_b; ldw=EE; }
    else { emb=trg_emb; W=dec_Wih; bias=dec_bih; out=tab_dec; ldw=EE+H2; }
    float acc = bias[n];
    const float* er = emb + (size_t)v*EE;
    const float* wr = W + (size_t)n*ldw;
    for (int k=0;k<EE;k++) acc += er[k]*wr[k];
    out[(size_t)v*H3 + n] = acc;
  } else {
    int n = tid;
    float acc = 0.f;
    const float* er = trg_emb + (size_t)v*EE;
    const float* wr = pre_W + (size_t)n*1280;
    for (int k=0;k<EE;k++) acc += er[k]*wr[k];
    tab_pre[(size_t)v*HH + n] = acc;
  }
}

// All fp32->bf16 weight conversions (incl. genW padded to 48 rows). grid(5424).
__global__ __launch_bounds__(256) void k_cvt_all(
    const float* __restrict__ eWhh_f, const float* __restrict__ eWhh_b,
    const float* __restrict__ dWhh, const float* __restrict__ dWih,
    const float* __restrict__ preW, const float* __restrict__ Wk,
    const float* __restrict__ Wq, const float* __restrict__ genW,
    u16* __restrict__ o1, u16* __restrict__ o2, u16* __restrict__ o3,
    u16* __restrict__ o4, u16* __restrict__ o5, u16* __restrict__ o6,
    u16* __restrict__ o7, u16* __restrict__ o8)
{
  int idx = blockIdx.x*256 + threadIdx.x;
  const float* src; u16* dst; int cols, ld, off, rel;
  if      (idx <  196608){ rel=idx;          src=eWhh_f; dst=o1; cols=256; ld=256;  off=0;   }
  else if (idx <  393216){ rel=idx-196608;   src=eWhh_b; dst=o2; cols=256; ld=256;  off=0;   }
  else if (idx <  589824){ rel=idx-393216;   src=dWhh;   dst=o3; cols=256; ld=256;  off=0;   }
  else if (idx <  983040){ rel=idx-589824;   src=dWih;   dst=o4; cols=512; ld=1024; off=512; }
  else if (idx < 1179648){ rel=idx-983040;   src=preW;   dst=o5; cols=768; ld=1280; off=512; }
  else if (idx < 1310720){ rel=idx-1179648;  src=Wk;     dst=o6; cols=512; ld=512;  off=0;   }
  else if (idx < 1376256){ rel=idx-1310720;  src=Wq;     dst=o7; cols=256; ld=256;  off=0;   }
  else if (idx < 1388544){
    rel=idx-1376256; int r=rel>>8, c2=rel&255;
    o8[rel] = (r<VV)? f2b(genW[(size_t)r*HH + c2]) : (u16)0;
    return;
  }
  else return;
  int r = rel/cols, c2 = rel - r*cols;
  dst[rel] = f2b(src[(size_t)r*ld + off + c2]);
}

// ---------------------------------------------------------------------------
// WHOLE encoder in one kernel, zero grid barriers. grid(32), block 512.
__global__ __launch_bounds__(512) void k_enc_all(const int* __restrict__ input,
    const u16* __restrict__ wb_f, const u16* __restrict__ wb_b,
    const float* __restrict__ bhh_f, const float* __restrict__ bhh_b,
    const float* __restrict__ tab_f, const float* __restrict__ tab_b,
    float* __restrict__ h_f, float* __restrict__ h_b, u16* __restrict__ enc_out)
{
  __shared__ float gh[32][772];
  __shared__ u16 hs[32][264];
  int bx = blockIdx.x;
  int dirb = bx>>4, mt = bx&15;
  int m0 = mt*32;
  int tid = threadIdx.x;
  const float* tab = dirb? tab_b : tab_f;
  const float* bhh = dirb? bhh_b : bhh_f;
  const u16* Wb = dirb? wb_b : wb_f;
  int c = tid & 255, rh = tid>>8;
  float b_r=bhh[c], b_z=bhh[c+256], b_n=bhh[c+512];
  float hreg[16];
  #pragma unroll
  for (int r=0;r<16;r++) hreg[r]=0.f;
  int wv = tid>>6, lane = tid&63, l15 = lane&15, kg=(lane>>4)*8;
  int n0w = wv*96;
  float* hOut = dirb? h_b : h_f;

  for (int s=1; s<=TT; s++){
    int tcol = dirb? (TT-s) : (s-1);
    #pragma unroll
    for (int r=0;r<16;r++){
      int row = rh*16 + r;
      int b = m0 + row;
      int tok = input[b*TT + tcol];
      const float* tg = tab + (size_t)tok*H3;
      float g0=0.f, g1=0.f, g2=0.f;
      if (s>1){ g0=gh[row][c]; g1=gh[row][c+256]; g2=gh[row][c+512]; }
      float rg = sigm(tg[c]     + g0 + b_r);
      float zg = sigm(tg[c+256] + g1 + b_z);
      float ng = tanh1(tg[c+512] + rg*(g2 + b_n));
      float hv = (1.f-zg)*ng + zg*hreg[r];
      hreg[r] = hv;
      u16 hb = f2b(hv);
      hs[row][c] = hb;
      enc_out[((size_t)b*TT + tcol)*H2 + (size_t)dirb*HH + c] = hb;
    }
    if (s==TT){
      #pragma unroll
      for (int r=0;r<16;r++)
        hOut[(size_t)(m0+rh*16+r)*HH + c] = hreg[r];
      break;
    }
    __syncthreads();
    f32x4 acc[2][6];
    #pragma unroll
    for (int rt=0;rt<2;rt++)
      #pragma unroll
      for (int nt=0;nt<6;nt++) acc[rt][nt]=(f32x4){0.f,0.f,0.f,0.f};
    const u16* ar0 = &hs[l15][0];
    const u16* ar1 = &hs[16+l15][0];
    for (int ko=0;ko<256;ko+=32){
      s16x8 a0 = *(const s16x8*)(ar0 + ko + kg);
      s16x8 a1 = *(const s16x8*)(ar1 + ko + kg);
      #pragma unroll
      for (int nt=0;nt<6;nt++){
        s16x8 bf = *(const s16x8*)(Wb + (size_t)(n0w+nt*16+l15)*HH + ko + kg);
        acc[0][nt] = __builtin_amdgcn_mfma_f32_16x16x32_bf16(a0, bf, acc[0][nt], 0,0,0);
        acc[1][nt] = __builtin_amdgcn_mfma_f32_16x16x32_bf16(a1, bf, acc[1][nt], 0,0,0);
      }
    }
    int q4 = (lane>>4)*4;
    #pragma unroll
    for (int rt=0;rt<2;rt++)
      #pragma unroll
      for (int nt=0;nt<6;nt++){
        int col = n0w + nt*16 + l15;
        #pragma unroll
        for (int j=0;j<4;j++)
          gh[rt*16 + q4 + j][col] = acc[rt][nt][j];
      }
    __syncthreads();
  }
}

// proj_key = enc_out @ Wk^T : MFMA. grid(1024), block 256.
__global__ __launch_bounds__(256) void k_pk(const u16* __restrict__ enc_out,
    const u16* __restrict__ wbk, u16* __restrict__ pk)
{
  int m0 = blockIdx.x*64;
  int tid = threadIdx.x, wv = tid>>6, lane = tid&63;
  int l15 = lane&15, kg = (lane>>4)*8;
  int n0 = wv*64;
  f32x4 acc[4][4];
  #pragma unroll
  for (int rt=0;rt<4;rt++)
    #pragma unroll
    for (int nt=0;nt<4;nt++) acc[rt][nt] = (f32x4){0.f,0.f,0.f,0.f};
  for (int ko=0; ko<512; ko+=32){
    s16x8 a[4], b[4];
    #pragma unroll
    for (int rt=0;rt<4;rt++) a[rt] = *(const s16x8*)(enc_out + (size_t)(m0+rt*16+l15)*H2 + ko + kg);
    #pragma unroll
    for (int nt=0;nt<4;nt++) b[nt] = *(const s16x8*)(wbk + (size_t)(n0+nt*16+l15)*H2 + ko + kg);
    #pragma unroll
    for (int rt=0;rt<4;rt++)
      #pragma unroll
      for (int nt=0;nt<4;nt++)
        acc[rt][nt] = __builtin_amdgcn_mfma_f32_16x16x32_bf16(a[rt], b[nt], acc[rt][nt], 0,0,0);
  }
  #pragma unroll
  for (int rt=0;rt<4;rt++){
    int rbase = m0 + rt*16 + (lane>>4)*4;
    #pragma unroll
    for (int nt=0;nt<4;nt++){
      int col = n0 + nt*16 + l15;
      #pragma unroll
      for (int j=0;j<4;j++)
        pk[(size_t)(rbase+j)*HH + col] = f2b(acc[rt][nt][j]);
    }
  }
}

// hidden = tanh([h_f|h_b] @ bridge_W^T + b). fp32 one-time. grid (4,8).
__global__ __launch_bounds__(256) void k_bridge(const float* __restrict__ h_f,
    const float* __restrict__ h_b, const float* __restrict__ bw,
    const float* __restrict__ bb, float* __restrict__ hd)
{
  __shared__ float As[32][68];
  __shared__ float Ws[32][68];
  int n0=blockIdx.x*64, m0=blockIdx.y*64, tid=threadIdx.x;
  int ar=tid>>2, ak=(tid&3)*8;
  int rt=tid>>4, ct=tid&15;
  float acc[4][4];
  #pragma unroll
  for (int j=0;j<4;j++){
    #pragma unroll
    for (int l=0;l<4;l++) acc[j][l]=0.f;
  }
  for (int ko=0;ko<512;ko+=32){
    int k0=ko+ak;
    const float* asrc = (k0<256)? (h_f + (size_t)(m0+ar)*HH + k0)
                                : (h_b + (size_t)(m0+ar)*HH + (k0-256));
    float4 a0=*(const float4*)asrc, a1=*(const float4*)(asrc+4);
    const float* wsrc = bw + (size_t)(n0+ar)*H2 + k0;
    float4 w0=*(const float4*)wsrc, w1=*(const float4*)(wsrc+4);
    __syncthreads();
    As[ak+0][ar]=a0.x; As[ak+1][ar]=a0.y; As[ak+2][ar]=a0.z; As[ak+3][ar]=a0.w;
    As[ak+4][ar]=a1.x; As[ak+5][ar]=a1.y; As[ak+6][ar]=a1.z; As[ak+7][ar]=a1.w;
    Ws[ak+0][ar]=w0.x; Ws[ak+1][ar]=w0.y; Ws[ak+2][ar]=w0.z; Ws[ak+3][ar]=w0.w;
    Ws[ak+4][ar]=w1.x; Ws[ak+5][ar]=w1.y; Ws[ak+6][ar]=w1.z; Ws[ak+7][ar]=w1.w;
    __syncthreads();
    #pragma unroll
    for (int kk=0;kk<32;kk++){
      float4 a=*(const float4*)&As[kk][rt*4];
      float4 w=*(const float4*)&Ws[kk][ct*4];
      float a4[4]={a.x,a.y,a.z,a.w};
      float w4[4]={w.x,w.y,w.z,w.w};
      #pragma unroll
      for (int j=0;j<4;j++){
        #pragma unroll
        for (int l=0;l<4;l++) acc[j][l]+=a4[j]*w4[l];
      }
    }
  }
  #pragma unroll
  for (int j=0;j<4;j++){
    int row=m0+rt*4+j;
    #pragma unroll
    for (int l=0;l<4;l++){
      int col=n0+ct*4+l;
      hd[(size_t)row*HH+col]=tanh1(acc[j][l]+bb[col]);
    }
  }
}

// ---------------------------------------------------------------------------
// Decoder: ONE block per batch row; pk resident in VGPRs, enc_out in LDS.
// Per-step global traffic = weights only (L2-resident). grid(512), block 256.
__global__ __launch_bounds__(256,1) void k_dec1(
    const int* __restrict__ input, const float* __restrict__ hd,
    const float* __restrict__ tab_dec, const float* __restrict__ tab_pre,
    const float* __restrict__ bhh, const float* __restrict__ We,
    const u16* __restrict__ wq, const u16* __restrict__ whh,
    const u16* __restrict__ wih, const u16* __restrict__ wpre,
    const u16* __restrict__ wgen,
    const u16* __restrict__ pk, const u16* __restrict__ enc_out,
    float* __restrict__ nll_part)
{
  __shared__ u16 encL[TT][H2];      // 128 KB, resident all 127 steps
  __shared__ float hL[HH];
  __shared__ float qL[HH];
  __shared__ float ctxL[H2];
  __shared__ float aL[TT];
  __shared__ float preL[HH];
  __shared__ float lgtL[48];
  __shared__ int stok[TT];

  int b = blockIdx.x, tid = threadIdx.x;
  int wv = tid>>6, lane = tid&63;

  // ---- one-time loads
  {
    const u16* src = enc_out + (size_t)b*TT*H2;
    u16* dst = &encL[0][0];
    for (int e = tid*8; e < TT*H2; e += 256*8)
      *(uint4*)(dst+e) = *(const uint4*)(src+e);
  }
  if (tid < TT) stok[tid] = input[b*TT + tid];
  float hreg = hd[(size_t)b*HH + tid];
  hL[tid] = hreg;
  u32 pkr[64];                       // pk[t0+tt][4*lane..+3], tt=0..31
  {
    int t0 = wv*32;
    const u32* pg = (const u32*)(pk + ((size_t)b*TT + t0)*HH) + lane*2;
    #pragma unroll
    for (int tt=0; tt<32; tt++){
      pkr[2*tt]   = pg[tt*128 + 0];
      pkr[2*tt+1] = pg[tt*128 + 1];
    }
  }
  float4 weL = *(const float4*)(We + lane*4);
  float b_r = bhh[tid], b_z = bhh[tid+256], b_n = bhh[tid+512];
  float nls = 0.f;
  __syncthreads();

  for (int j=0; j<TM1; j++){
    // A: q = h @ Wq^T
    qL[tid] = dotw(wq + (size_t)tid*HH, hL, HH);
    __syncthreads();
    // B: e[t] = We . tanh(q + pk[t]) (wave wv owns t in [32wv,32wv+32))
    {
      float4 qq = *(const float4*)&qL[lane*4];
      int t0 = wv*32;
      #pragma unroll
      for (int tt=0; tt<32; tt++){
        u32 p0 = pkr[2*tt], p1 = pkr[2*tt+1];
        float s = tanh1(qq.x+bfl(p0))*weL.x + tanh1(qq.y+bfh(p0))*weL.y
                + tanh1(qq.z+bfl(p1))*weL.z + tanh1(qq.w+bfh(p1))*weL.w;
        #pragma unroll
        for (int off=32; off; off>>=1) s += __shfl_xor(s, off);
        if (lane==0) aL[t0+tt] = stok[t0+tt] ? s : NEGF;
      }
    }
    __syncthreads();
    if (wv==0){
      float v0 = aL[lane], v1 = aL[64+lane];
      float m = fmaxf(v0,v1);
      #pragma unroll
      for (int off=32; off; off>>=1) m = fmaxf(m, __shfl_xor(m,off));
      float p0 = __expf(v0-m), p1 = __expf(v1-m);
      float s = p0+p1;
      #pragma unroll
      for (int off=32; off; off>>=1) s += __shfl_xor(s,off);
      float inv = 1.f/s;
      aL[lane] = p0*inv; aL[64+lane] = p1*inv;
    }
    __syncthreads();
    // C: ctx[d] = sum_t a[t]*enc[t][d]; thread owns dims (2tid, 2tid+1)
    {
      float c0=0.f, c1=0.f;
      const u32* er = (const u32*)&encL[0][0] + tid;
      #pragma unroll 4
      for (int t=0; t<TT; t++){
        float a = aL[t];
        u32 e2 = er[t*256];
        c0 += a*bfl(e2); c1 += a*bfh(e2);
      }
      ctxL[2*tid] = c0; ctxL[2*tid+1] = c1;
    }
    __syncthreads();
    // D: gh (K=256), gic (K=512), gates -> h_{j+1}
    {
      float g0 = dotw(whh + (size_t)tid*HH,       hL, HH);
      float g1 = dotw(whh + (size_t)(tid+256)*HH, hL, HH);
      float g2 = dotw(whh + (size_t)(tid+512)*HH, hL, HH);
      float i0 = dotw(wih + (size_t)tid*H2,       ctxL, H2);
      float i1 = dotw(wih + (size_t)(tid+256)*H2, ctxL, H2);
      float i2 = dotw(wih + (size_t)(tid+512)*H2, ctxL, H2);
      int tok = stok[j];
      const float* tg = tab_dec + (size_t)tok*H3;
      float rg = sigm(tg[tid]     + i0 + g0 + b_r);
      float zg = sigm(tg[tid+256] + i1 + g1 + b_z);
      float ng = tanh1(tg[tid+512] + i2 + rg*(g2 + b_n));
      hreg = (1.f-zg)*ng + zg*hreg;
      __syncthreads();                 // all reads of old hL done
      hL[tid] = hreg;
    }
    __syncthreads();
    // E: pre = tab_pre[tok] + [h_new | ctx] @ wpre^T
    {
      int tok = stok[j];
      preL[tid] = tab_pre[(size_t)tok*HH + tid]
                + dotw(wpre + (size_t)tid*H3,      hL,   HH)
                + dotw(wpre + (size_t)tid*H3 + HH, ctxL, H2);
    }
    __syncthreads();
    // F: logits (wave0 threads 0..47) + nll (wave0); other waves proceed to A
    if (tid < 48) lgtL[tid] = dotw(wgen + (size_t)tid*HH, preL, HH);
    if (wv==0){
      float lg = (lane<VV)? lgtL[lane] : NEGF;   // same-wave LDS, ordered
      float m = lg;
      #pragma unroll
      for (int off=32; off; off>>=1) m = fmaxf(m, __shfl_xor(m,off));
      float pe = (lane<VV)? __expf(lg-m) : 0.f;
      float ss = pe;
      #pragma unroll
      for (int off=32; off; off>>=1) ss += __shfl_xor(ss,off);
      int ty = stok[j+1];
      float lty = __shfl(lg, ty);
      if (lane==0 && ty!=0) nls += m + __logf(ss) - lty;
    }
  }
  if (tid==0) nll_part[b] = nls;
}

__global__ __launch_bounds__(256) void k_loss(const float* __restrict__ nll_part,
                                              float* __restrict__ out)
{
  __shared__ float sm[256];
  int tid=threadIdx.x;
  float s = nll_part[tid] + nll_part[tid+256];
  sm[tid]=s; __syncthreads();
  for (int off=128; off; off>>=1){
    if (tid<off) sm[tid]+=sm[tid+off];
    __syncthreads();
  }
  if (tid==0) out[0]=sm[0];
}

extern "C" void kernel_launch(void* const* d_in, const int* in_sizes, int n_in,
                              void* d_out, int out_size, void* d_ws, size_t ws_size,
                              hipStream_t stream)
{
  const int*   input    = (const int*)  d_in[0];
  const float* src_emb  = (const float*)d_in[1];
  const float* trg_emb  = (const float*)d_in[2];
  const float* eWih_f   = (const float*)d_in[3];
  const float* eWhh_f   = (const float*)d_in[4];
  const float* ebih_f   = (const float*)d_in[5];
  const float* ebhh_f   = (const float*)d_in[6];
  const float* eWih_b   = (const float*)d_in[7];
  const float* eWhh_b   = (const float*)d_in[8];
  const float* ebih_b   = (const float*)d_in[9];
  const float* ebhh_b   = (const float*)d_in[10];
  const float* bridge_W = (const float*)d_in[11];
  const float* bridge_b = (const float*)d_in[12];
  const float* attn_Wk  = (const float*)d_in[13];
  const float* attn_Wq  = (const float*)d_in[14];
  const float* attn_We  = (const float*)d_in[15];
  const float* dec_Wih  = (const float*)d_in[16];
  const float* dec_Whh  = (const float*)d_in[17];
  const float* dec_bih  = (const float*)d_in[18];
  const float* dec_bhh  = (const float*)d_in[19];
  const float* pre_W    = (const float*)d_in[20];
  const float* gen_W    = (const float*)d_in[21];

  float* F = (float*)d_ws;
  size_t o=0;
  float* tab_gi_f = F+o; o+=(size_t)VV*H3;
  float* tab_gi_b = F+o; o+=(size_t)VV*H3;
  float* tab_dec  = F+o; o+=(size_t)VV*H3;
  float* tab_pre  = F+o; o+=(size_t)VV*HH;
  float* h_f      = F+o; o+=(size_t)BB*HH;
  float* h_b      = F+o; o+=(size_t)BB*HH;
  float* hd       = F+o; o+=(size_t)BB*HH;
  float* nll_part = F+o; o+=(size_t)BB;
  u16* U = (u16*)(F+o);
  size_t uo=0;
  u16* enc_out = U+uo; uo+=(size_t)BB*TT*H2;
  u16* pk      = U+uo; uo+=(size_t)BB*TT*HH;
  u16* wb_ehh_f= U+uo; uo+=(size_t)H3*HH;
  u16* wb_ehh_b= U+uo; uo+=(size_t)H3*HH;
  u16* wb_dhh  = U+uo; uo+=(size_t)H3*HH;
  u16* wb_dih  = U+uo; uo+=(size_t)H3*H2;
  u16* wb_pre  = U+uo; uo+=(size_t)HH*H3;
  u16* wb_wk   = U+uo; uo+=(size_t)HH*H2;
  u16* wb_wq   = U+uo; uo+=(size_t)HH*HH;
  u16* wb_gen  = U+uo; uo+=(size_t)48*HH;

  dim3 blk(256,1,1);
  k_tables<<<dim3(VV,10),blk,0,stream>>>(src_emb,trg_emb,eWih_f,ebih_f,eWih_b,ebih_b,
                                         dec_Wih,dec_bih,pre_W,
                                         tab_gi_f,tab_gi_b,tab_dec,tab_pre);
  k_cvt_all<<<dim3(5424),blk,0,stream>>>(eWhh_f,eWhh_b,dec_Whh,dec_Wih,pre_W,attn_Wk,attn_Wq,gen_W,
                                         wb_ehh_f,wb_ehh_b,wb_dhh,wb_dih,wb_pre,wb_wk,wb_wq,wb_gen);
  k_enc_all<<<dim3(32),dim3(512),0,stream>>>(input,wb_ehh_f,wb_ehh_b,ebhh_f,ebhh_b,
                                             tab_gi_f,tab_gi_b,h_f,h_b,enc_out);
  k_pk<<<dim3(1024),blk,0,stream>>>(enc_out,wb_wk,pk);
  k_bridge<<<dim3(4,8),blk,0,stream>>>(h_f,h_b,bridge_W,bridge_b,hd);
  k_dec1<<<dim3(BB),blk,0,stream>>>(input,hd,tab_dec,tab_pre,dec_bhh,attn_We,
                                    wb_wq,wb_dhh,wb_dih,wb_pre,wb_gen,
                                    pk,enc_out,nll_part);
  k_loss<<<dim3(1),blk,0,stream>>>(nll_part,(float*)d_out);
}

// Round 6
// 12366.259 us; speedup vs baseline: 1.6943x; 1.4855x over previous
//
#include <hip/hip_runtime.h>

#define BB 512
#define TT 128
#define EE 512
#define HH 256
#define VV 39
#define H3 768
#define H2 512
#define TM1 127
#define NEGF (-3.402823466e38f)

typedef unsigned short u16;
typedef unsigned int u32;
typedef __attribute__((ext_vector_type(8))) short s16x8;
typedef __attribute__((ext_vector_type(4))) float f32x4;

__device__ __forceinline__ float b2f(u16 u){ u32 x=((u32)u)<<16; return __uint_as_float(x); }
__device__ __forceinline__ u16 f2b(float f){ u32 x=__float_as_uint(f); u32 r=(x+0x7fffu+((x>>16)&1u))>>16; return (u16)r; }
__device__ __forceinline__ float sigm(float x){ return 1.f/(1.f+__expf(-x)); }
__device__ __forceinline__ float tanh1(float x){ float t=__expf(2.f*x); return 1.f-2.f/(t+1.f); }

#define MFMA __builtin_amdgcn_mfma_f32_16x16x32_bf16

// ---------------------------------------------------------------------------
// Per-token input-projection tables (V=39).
__global__ __launch_bounds__(256) void k_tables(
    const float* __restrict__ src_emb, const float* __restrict__ trg_emb,
    const float* __restrict__ Wih_f, const float* __restrict__ bih_f,
    const float* __restrict__ Wih_b, const float* __restrict__ bih_b,
    const float* __restrict__ dec_Wih, const float* __restrict__ dec_bih,
    const float* __restrict__ pre_W,
    float* __restrict__ tab_gi_f, float* __restrict__ tab_gi_b,
    float* __restrict__ tab_dec, float* __restrict__ tab_pre)
{
  int v = blockIdx.x;
  int y = blockIdx.y;
  int tid = threadIdx.x;
  if (y < 9){
    int seg = y/3, part = y%3;
    int n = part*256 + tid;
    const float* emb; const float* W; const float* bias; float* out; int ldw;
    if (seg==0){ emb=src_emb; W=Wih_f; bias=bih_f; out=tab_gi_f; ldw=EE; }
    else if (seg==1){ emb=src_emb; W=Wih_b; bias=bih_b; out=tab_gi_b; ldw=EE; }
    else { emb=trg_emb; W=dec_Wih; bias=dec_bih; out=tab_dec; ldw=EE+H2; }
    float acc = bias[n];
    const float* er = emb + (size_t)v*EE;
    const float* wr = W + (size_t)n*ldw;
    for (int k=0;k<EE;k++) acc += er[k]*wr[k];
    out[(size_t)v*H3 + n] = acc;
  } else {
    int n = tid;
    float acc = 0.f;
    const float* er = trg_emb + (size_t)v*EE;
    const float* wr = pre_W + (size_t)n*1280;
    for (int k=0;k<EE;k++) acc += er[k]*wr[k];
    tab_pre[(size_t)v*HH + n] = acc;
  }
}

// All fp32->bf16 weight conversions. grid(5440).
__global__ __launch_bounds__(256) void k_cvt_all(
    const float* __restrict__ eWhh_f, const float* __restrict__ eWhh_b,
    const float* __restrict__ dWhh, const float* __restrict__ dWih,
    const float* __restrict__ Wk, const float* __restrict__ Wq,
    const float* __restrict__ preW, const float* __restrict__ genW,
    u16* __restrict__ o1, u16* __restrict__ o2, u16* __restrict__ o3,
    u16* __restrict__ o4, u16* __restrict__ o5, u16* __restrict__ o6,
    u16* __restrict__ o7, u16* __restrict__ o8, u16* __restrict__ o9)
{
  int idx = blockIdx.x*256 + threadIdx.x;
  const float* src; u16* dst; int cols, ld, off, rel;
  if      (idx <  196608){ rel=idx;          src=eWhh_f; dst=o1; cols=256; ld=256;  off=0;   }
  else if (idx <  393216){ rel=idx-196608;   src=eWhh_b; dst=o2; cols=256; ld=256;  off=0;   }
  else if (idx <  589824){ rel=idx-393216;   src=dWhh;   dst=o3; cols=256; ld=256;  off=0;   }
  else if (idx <  983040){ rel=idx-589824;   src=dWih;   dst=o4; cols=512; ld=1024; off=512; }
  else if (idx < 1114112){ rel=idx-983040;   src=Wk;     dst=o5; cols=512; ld=512;  off=0;   }
  else if (idx < 1179648){ rel=idx-1114112;  src=Wq;     dst=o6; cols=256; ld=256;  off=0;   }
  else if (idx < 1245184){ rel=idx-1179648;  src=preW;   dst=o7; cols=256; ld=1280; off=512; }
  else if (idx < 1376256){ rel=idx-1245184;  src=preW;   dst=o8; cols=512; ld=1280; off=768; }
  else if (idx < 1392640){
    rel=idx-1376256; int r=rel>>8, c2=rel&255;
    o9[rel] = (r<VV)? f2b(genW[(size_t)r*HH + c2]) : (u16)0;
    return;
  }
  else return;
  int r = rel/cols, c2 = rel - r*cols;
  dst[rel] = f2b(src[(size_t)r*ld + off + c2]);
}

// ---------------------------------------------------------------------------
// WHOLE encoder in one kernel, zero grid barriers. grid(32), block 512.
__global__ __launch_bounds__(512) void k_enc_all(const int* __restrict__ input,
    const u16* __restrict__ wb_f, const u16* __restrict__ wb_b,
    const float* __restrict__ bhh_f, const float* __restrict__ bhh_b,
    const float* __restrict__ tab_f, const float* __restrict__ tab_b,
    float* __restrict__ h_f, float* __restrict__ h_b, u16* __restrict__ enc_out)
{
  __shared__ float gh[32][772];
  __shared__ u16 hs[32][264];
  int bx = blockIdx.x;
  int dirb = bx>>4, mt = bx&15;
  int m0 = mt*32;
  int tid = threadIdx.x;
  const float* tab = dirb? tab_b : tab_f;
  const float* bhh = dirb? bhh_b : bhh_f;
  const u16* Wb = dirb? wb_b : wb_f;
  int c = tid & 255, rh = tid>>8;
  float b_r=bhh[c], b_z=bhh[c+256], b_n=bhh[c+512];
  float hreg[16];
  #pragma unroll
  for (int r=0;r<16;r++) hreg[r]=0.f;
  int wv = tid>>6, lane = tid&63, l15 = lane&15, kg=(lane>>4)*8;
  int n0w = wv*96;
  float* hOut = dirb? h_b : h_f;

  for (int s=1; s<=TT; s++){
    int tcol = dirb? (TT-s) : (s-1);
    #pragma unroll
    for (int r=0;r<16;r++){
      int row = rh*16 + r;
      int b = m0 + row;
      int tok = input[b*TT + tcol];
      const float* tg = tab + (size_t)tok*H3;
      float g0=0.f, g1=0.f, g2=0.f;
      if (s>1){ g0=gh[row][c]; g1=gh[row][c+256]; g2=gh[row][c+512]; }
      float rg = sigm(tg[c]     + g0 + b_r);
      float zg = sigm(tg[c+256] + g1 + b_z);
      float ng = tanh1(tg[c+512] + rg*(g2 + b_n));
      float hv = (1.f-zg)*ng + zg*hreg[r];
      hreg[r] = hv;
      u16 hb = f2b(hv);
      hs[row][c] = hb;
      enc_out[((size_t)b*TT + tcol)*H2 + (size_t)dirb*HH + c] = hb;
    }
    if (s==TT){
      #pragma unroll
      for (int r=0;r<16;r++)
        hOut[(size_t)(m0+rh*16+r)*HH + c] = hreg[r];
      break;
    }
    __syncthreads();
    f32x4 acc[2][6];
    #pragma unroll
    for (int rt=0;rt<2;rt++)
      #pragma unroll
      for (int nt=0;nt<6;nt++) acc[rt][nt]=(f32x4){0.f,0.f,0.f,0.f};
    const u16* ar0 = &hs[l15][0];
    const u16* ar1 = &hs[16+l15][0];
    for (int ko=0;ko<256;ko+=32){
      s16x8 a0 = *(const s16x8*)(ar0 + ko + kg);
      s16x8 a1 = *(const s16x8*)(ar1 + ko + kg);
      #pragma unroll
      for (int nt=0;nt<6;nt++){
        s16x8 bf = *(const s16x8*)(Wb + (size_t)(n0w+nt*16+l15)*HH + ko + kg);
        acc[0][nt] = MFMA(a0, bf, acc[0][nt], 0,0,0);
        acc[1][nt] = MFMA(a1, bf, acc[1][nt], 0,0,0);
      }
    }
    int q4 = (lane>>4)*4;
    #pragma unroll
    for (int rt=0;rt<2;rt++)
      #pragma unroll
      for (int nt=0;nt<6;nt++){
        int col = n0w + nt*16 + l15;
        #pragma unroll
        for (int j=0;j<4;j++)
          gh[rt*16 + q4 + j][col] = acc[rt][nt][j];
      }
    __syncthreads();
  }
}

// proj_key = enc_out @ Wk^T : MFMA. grid(1024), block 256.
__global__ __launch_bounds__(256) void k_pk(const u16* __restrict__ enc_out,
    const u16* __restrict__ wbk, u16* __restrict__ pk)
{
  int m0 = blockIdx.x*64;
  int tid = threadIdx.x, wv = tid>>6, lane = tid&63;
  int l15 = lane&15, kg = (lane>>4)*8;
  int n0 = wv*64;
  f32x4 acc[4][4];
  #pragma unroll
  for (int rt=0;rt<4;rt++)
    #pragma unroll
    for (int nt=0;nt<4;nt++) acc[rt][nt] = (f32x4){0.f,0.f,0.f,0.f};
  for (int ko=0; ko<512; ko+=32){
    s16x8 a[4], b[4];
    #pragma unroll
    for (int rt=0;rt<4;rt++) a[rt] = *(const s16x8*)(enc_out + (size_t)(m0+rt*16+l15)*H2 + ko + kg);
    #pragma unroll
    for (int nt=0;nt<4;nt++) b[nt] = *(const s16x8*)(wbk + (size_t)(n0+nt*16+l15)*H2 + ko + kg);
    #pragma unroll
    for (int rt=0;rt<4;rt++)
      #pragma unroll
      for (int nt=0;nt<4;nt++)
        acc[rt][nt] = MFMA(a[rt], b[nt], acc[rt][nt], 0,0,0);
  }
  #pragma unroll
  for (int rt=0;rt<4;rt++){
    int rbase = m0 + rt*16 + (lane>>4)*4;
    #pragma unroll
    for (int nt=0;nt<4;nt++){
      int col = n0 + nt*16 + l15;
      #pragma unroll
      for (int j=0;j<4;j++)
        pk[(size_t)(rbase+j)*HH + col] = f2b(acc[rt][nt][j]);
    }
  }
}

// hidden = tanh([h_f|h_b] @ bridge_W^T + b) -> hst. grid (4,8).
__global__ __launch_bounds__(256) void k_bridge(const float* __restrict__ h_f,
    const float* __restrict__ h_b, const float* __restrict__ bw,
    const float* __restrict__ bb, float* __restrict__ hst)
{
  __shared__ float As[32][68];
  __shared__ float Ws[32][68];
  int n0=blockIdx.x*64, m0=blockIdx.y*64, tid=threadIdx.x;
  int ar=tid>>2, ak=(tid&3)*8;
  int rt=tid>>4, ct=tid&15;
  float acc[4][4];
  #pragma unroll
  for (int j=0;j<4;j++){
    #pragma unroll
    for (int l=0;l<4;l++) acc[j][l]=0.f;
  }
  for (int ko=0;ko<512;ko+=32){
    int k0=ko+ak;
    const float* asrc = (k0<256)? (h_f + (size_t)(m0+ar)*HH + k0)
                                : (h_b + (size_t)(m0+ar)*HH + (k0-256));
    float4 a0=*(const float4*)asrc, a1=*(const float4*)(asrc+4);
    const float* wsrc = bw + (size_t)(n0+ar)*H2 + k0;
    float4 w0=*(const float4*)wsrc, w1=*(const float4*)(wsrc+4);
    __syncthreads();
    As[ak+0][ar]=a0.x; As[ak+1][ar]=a0.y; As[ak+2][ar]=a0.z; As[ak+3][ar]=a0.w;
    As[ak+4][ar]=a1.x; As[ak+5][ar]=a1.y; As[ak+6][ar]=a1.z; As[ak+7][ar]=a1.w;
    Ws[ak+0][ar]=w0.x; Ws[ak+1][ar]=w0.y; Ws[ak+2][ar]=w0.z; Ws[ak+3][ar]=w0.w;
    Ws[ak+4][ar]=w1.x; Ws[ak+5][ar]=w1.y; Ws[ak+6][ar]=w1.z; Ws[ak+7][ar]=w1.w;
    __syncthreads();
    #pragma unroll
    for (int kk=0;kk<32;kk++){
      float4 a=*(const float4*)&As[kk][rt*4];
      float4 w=*(const float4*)&Ws[kk][ct*4];
      float a4[4]={a.x,a.y,a.z,a.w};
      float w4[4]={w.x,w.y,w.z,w.w};
      #pragma unroll
      for (int j=0;j<4;j++){
        #pragma unroll
        for (int l=0;l<4;l++) acc[j][l]+=a4[j]*w4[l];
      }
    }
  }
  #pragma unroll
  for (int j=0;j<4;j++){
    int row=m0+rt*4+j;
    #pragma unroll
    for (int l=0;l<4;l++){
      int col=n0+ct*4+l;
      hst[(size_t)row*HH+col]=tanh1(acc[j][l]+bb[col]);
    }
  }
}

// Bootstrap: q0 = h0@Wq, gh0 = h0@Whh, zero nll. grid(32), block 256.
__global__ __launch_bounds__(256) void k_boot(
    const float* __restrict__ hst, const u16* __restrict__ whh,
    const u16* __restrict__ wq, float* __restrict__ ghg,
    float* __restrict__ qg, float* __restrict__ nll)
{
  __shared__ u16 hsb[16][264];
  int bx=blockIdx.x, tid=threadIdx.x;
  int wv=tid>>6, lane=tid&63, l15=lane&15, kg=(lane>>4)*8;
  int b0=bx*16;
  {
    int c=tid;
    for (int r=0;r<16;r++) hsb[r][c] = f2b(hst[(size_t)(b0+r)*HH + c]);
  }
  if (tid<16) nll[b0+tid] = 0.f;
  __syncthreads();
  int rr = (lane>>4)*4;
  for (int nt=0;nt<12;nt++){
    int n0 = wv*192 + nt*16;
    f32x4 acc = (f32x4){0.f,0.f,0.f,0.f};
    for (int ko=0;ko<256;ko+=32){
      s16x8 a = *(const s16x8*)&hsb[l15][ko+kg];
      s16x8 bf = *(const s16x8*)(whh + (size_t)(n0+l15)*HH + ko + kg);
      acc = MFMA(a, bf, acc, 0,0,0);
    }
    #pragma unroll
    for (int jr=0;jr<4;jr++)
      ghg[(size_t)(b0+rr+jr)*H3 + n0 + l15] = acc[jr];
  }
  #pragma unroll
  for (int nt=0;nt<4;nt++){
    int n0 = wv*64 + nt*16;
    f32x4 acc = (f32x4){0.f,0.f,0.f,0.f};
    for (int ko=0;ko<256;ko+=32){
      s16x8 a = *(const s16x8*)&hsb[l15][ko+kg];
      s16x8 bf = *(const s16x8*)(wq + (size_t)(n0+l15)*HH + ko + kg);
      acc = MFMA(a, bf, acc, 0,0,0);
    }
    #pragma unroll
    for (int jr=0;jr<4;jr++)
      qg[(size_t)(b0+rr+jr)*HH + n0 + l15] = acc[jr];
  }
}

// ---------------------------------------------------------------------------
// Attention step: one block per row, 512 thr (8 waves). Streams pk+enc.
__global__ __launch_bounds__(512) void k_attn(
    const int* __restrict__ input, const float* __restrict__ qg,
    const u16* __restrict__ pk, const u16* __restrict__ enc_out,
    const float* __restrict__ We, u16* __restrict__ ctx_bf)
{
  __shared__ float aL[TT];
  __shared__ int stok[TT];
  __shared__ float part[8][512];
  int b = blockIdx.x, tid = threadIdx.x;
  int wv = tid>>6, lane = tid&63, l32 = lane&31;
  if (tid < TT) stok[tid] = input[b*TT + tid];
  const float* qb = qg + (size_t)b*HH + l32*8;
  float4 q0 = *(const float4*)qb;
  float4 q1 = *(const float4*)(qb+4);
  float4 w0 = *(const float4*)(We + l32*8);
  float4 w1 = *(const float4*)(We + l32*8 + 4);
  const u16* pkb = pk + (size_t)b*TT*HH + l32*8;
  __syncthreads();
  // e[t] = We . tanh(q + pk[t]); wave wv: t in [16wv,16wv+16), 2 t per iter
  #pragma unroll
  for (int it=0; it<8; it++){
    int t = wv*16 + it*2 + (lane>>5);
    s16x8 kv = *(const s16x8*)(pkb + (size_t)t*HH);
    float s = tanh1(q0.x + b2f((u16)kv[0]))*w0.x
            + tanh1(q0.y + b2f((u16)kv[1]))*w0.y
            + tanh1(q0.z + b2f((u16)kv[2]))*w0.z
            + tanh1(q0.w + b2f((u16)kv[3]))*w0.w
            + tanh1(q1.x + b2f((u16)kv[4]))*w1.x
            + tanh1(q1.y + b2f((u16)kv[5]))*w1.y
            + tanh1(q1.z + b2f((u16)kv[6]))*w1.z
            + tanh1(q1.w + b2f((u16)kv[7]))*w1.w;
    #pragma unroll
    for (int off=16; off; off>>=1) s += __shfl_xor(s, off);
    if (l32==0) aL[t] = stok[t] ? s : NEGF;
  }
  __syncthreads();
  if (wv==0){
    float v0 = aL[lane], v1 = aL[64+lane];
    float m = fmaxf(v0,v1);
    #pragma unroll
    for (int off=32; off; off>>=1) m = fmaxf(m, __shfl_xor(m,off));
    float p0 = __expf(v0-m), p1 = __expf(v1-m);
    float s = p0+p1;
    #pragma unroll
    for (int off=32; off; off>>=1) s += __shfl_xor(s,off);
    float inv = 1.f/s;
    aL[lane] = p0*inv; aL[64+lane] = p1*inv;
  }
  __syncthreads();
  // ctx: wave wv: t in [16wv,16wv+16); lane owns dims lane*8..+7
  float cacc[8];
  #pragma unroll
  for (int e=0;e<8;e++) cacc[e]=0.f;
  const u16* eb = enc_out + (size_t)b*TT*H2 + lane*8;
  int t0 = wv*16;
  #pragma unroll
  for (int it=0; it<16; it++){
    s16x8 ev = *(const s16x8*)(eb + (size_t)(t0+it)*H2);
    float a = aL[t0+it];
    #pragma unroll
    for (int e=0;e<8;e++) cacc[e] += a*b2f((u16)ev[e]);
  }
  #pragma unroll
  for (int e=0;e<8;e++) part[wv][lane*8+e] = cacc[e];
  __syncthreads();
  float s2 = 0.f;
  #pragma unroll
  for (int w=0;w<8;w++) s2 += part[w][tid];
  ctx_bf[(size_t)b*H2 + tid] = f2b(s2);
}

// ---------------------------------------------------------------------------
// Decoder batch step: 32 blocks x 16 rows, 256 thr. All GEMMs via M=16 MFMA.
__global__ __launch_bounds__(256) void k_dstep(int j,
    const int* __restrict__ input,
    const float* __restrict__ tab_dec, const float* __restrict__ tab_pre,
    const float* __restrict__ bhh,
    const u16* __restrict__ whh, const u16* __restrict__ wih,
    const u16* __restrict__ wq, const u16* __restrict__ wph,
    const u16* __restrict__ wpc, const u16* __restrict__ wgen,
    const u16* __restrict__ ctx_bf, float* __restrict__ hst,
    float* __restrict__ qg, float* __restrict__ ghg,
    float* __restrict__ nll)
{
  __shared__ u16 cs[16][520];
  __shared__ u16 hsb[16][264];
  __shared__ float gicL[16][776];
  __shared__ float pcL[16][256];
  __shared__ u16 preb[16][264];
  __shared__ float lgt[16][64];
  __shared__ int stokL[16];
  int bx = blockIdx.x, tid = threadIdx.x;
  int wv = tid>>6, lane = tid&63, l15 = lane&15, kg = (lane>>4)*8;
  int b0 = bx*16;
  int rr = (lane>>4)*4;

  for (int idx = tid; idx < 16*64; idx += 256){
    int r = idx>>6, cc = (idx&63)*8;
    *(uint4*)&cs[r][cc] = *(const uint4*)(ctx_bf + (size_t)(b0+r)*H2 + cc);
  }
  if (tid < 16) stokL[tid] = input[(b0+tid)*TT + j];
  __syncthreads();

  // gic = ctx @ Wih_ctx^T (N=768, K=512)
  for (int nt=0; nt<12; nt++){
    int n0 = wv*192 + nt*16;
    f32x4 acc = (f32x4){0.f,0.f,0.f,0.f};
    for (int ko=0; ko<512; ko+=32){
      s16x8 a = *(const s16x8*)&cs[l15][ko+kg];
      s16x8 bf = *(const s16x8*)(wih + (size_t)(n0+l15)*H2 + ko + kg);
      acc = MFMA(a, bf, acc, 0,0,0);
    }
    #pragma unroll
    for (int jr=0;jr<4;jr++) gicL[rr+jr][n0+l15] = acc[jr];
  }
  // preCtx = ctx @ wpre_ctx^T (N=256, K=512)
  #pragma unroll
  for (int nt=0; nt<4; nt++){
    int n0 = wv*64 + nt*16;
    f32x4 acc = (f32x4){0.f,0.f,0.f,0.f};
    for (int ko=0; ko<512; ko+=32){
      s16x8 a = *(const s16x8*)&cs[l15][ko+kg];
      s16x8 bf = *(const s16x8*)(wpc + (size_t)(n0+l15)*H2 + ko + kg);
      acc = MFMA(a, bf, acc, 0,0,0);
    }
    #pragma unroll
    for (int jr=0;jr<4;jr++) pcL[rr+jr][n0+l15] = acc[jr];
  }
  __syncthreads();

  // gates -> h_{j+1}
  {
    int c = tid;
    float b_r = bhh[c], b_z = bhh[c+256], b_n = bhh[c+512];
    for (int r=0;r<16;r++){
      int b = b0+r;
      const float* tg = tab_dec + (size_t)stokL[r]*H3;
      const float* gr = ghg + (size_t)b*H3;
      float rg = sigm(tg[c]     + gicL[r][c]     + gr[c]     + b_r);
      float zg = sigm(tg[c+256] + gicL[r][c+256] + gr[c+256] + b_z);
      float ng = tanh1(tg[c+512] + gicL[r][c+512] + rg*(gr[c+512] + b_n));
      float hv = (1.f-zg)*ng + zg*hst[(size_t)b*HH + c];
      hst[(size_t)b*HH + c] = hv;
      hsb[r][c] = f2b(hv);
    }
  }
  __syncthreads();

  // gh_{j+1} = h @ Whh^T (N=768, K=256)
  for (int nt=0;nt<12;nt++){
    int n0 = wv*192 + nt*16;
    f32x4 acc = (f32x4){0.f,0.f,0.f,0.f};
    for (int ko=0;ko<256;ko+=32){
      s16x8 a = *(const s16x8*)&hsb[l15][ko+kg];
      s16x8 bf = *(const s16x8*)(whh + (size_t)(n0+l15)*HH + ko + kg);
      acc = MFMA(a, bf, acc, 0,0,0);
    }
    #pragma unroll
    for (int jr=0;jr<4;jr++)
      ghg[(size_t)(b0+rr+jr)*H3 + n0 + l15] = acc[jr];
  }
  // q_{j+1} = h @ Wq^T (N=256, K=256)
  #pragma unroll
  for (int nt=0;nt<4;nt++){
    int n0 = wv*64 + nt*16;
    f32x4 acc = (f32x4){0.f,0.f,0.f,0.f};
    for (int ko=0;ko<256;ko+=32){
      s16x8 a = *(const s16x8*)&hsb[l15][ko+kg];
      s16x8 bf = *(const s16x8*)(wq + (size_t)(n0+l15)*HH + ko + kg);
      acc = MFMA(a, bf, acc, 0,0,0);
    }
    #pragma unroll
    for (int jr=0;jr<4;jr++)
      qg[(size_t)(b0+rr+jr)*HH + n0 + l15] = acc[jr];
  }
  // pre = tab_pre + preCtx + h @ wpre_h^T (N=256, K=256)
  #pragma unroll
  for (int nt=0;nt<4;nt++){
    int n0 = wv*64 + nt*16;
    f32x4 acc = (f32x4){0.f,0.f,0.f,0.f};
    for (int ko=0;ko<256;ko+=32){
      s16x8 a = *(const s16x8*)&hsb[l15][ko+kg];
      s16x8 bf = *(const s16x8*)(wph + (size_t)(n0+l15)*HH + ko + kg);
      acc = MFMA(a, bf, acc, 0,0,0);
    }
    #pragma unroll
    for (int jr=0;jr<4;jr++){
      int r = rr+jr;
      float pv = acc[jr] + pcL[r][n0+l15] + tab_pre[(size_t)stokL[r]*HH + n0 + l15];
      preb[r][n0+l15] = f2b(pv);
    }
  }
  __syncthreads();

  // logits = pre @ genW^T (N=64 padded, K=256); wave wv -> tile wv
  {
    int n0 = wv*16;
    f32x4 acc = (f32x4){0.f,0.f,0.f,0.f};
    for (int ko=0;ko<256;ko+=32){
      s16x8 a = *(const s16x8*)&preb[l15][ko+kg];
      s16x8 bf = *(const s16x8*)(wgen + (size_t)(n0+l15)*HH + ko + kg);
      acc = MFMA(a, bf, acc, 0,0,0);
    }
    #pragma unroll
    for (int jr=0;jr<4;jr++) lgt[rr+jr][n0+l15] = acc[jr];
  }
  __syncthreads();

  // nll: 16-lane group per row
  {
    int r = wv*4 + (lane>>4);
    float v0 = lgt[r][l15];
    float v1 = lgt[r][l15+16];
    float v2 = (l15<7)? lgt[r][l15+32] : NEGF;
    float m = fmaxf(fmaxf(v0,v1),v2);
    #pragma unroll
    for (int off=8; off; off>>=1) m = fmaxf(m, __shfl_xor(m,off));
    float pe = __expf(v0-m) + __expf(v1-m) + ((l15<7)? __expf(v2-m) : 0.f);
    #pragma unroll
    for (int off=8; off; off>>=1) pe += __shfl_xor(pe,off);
    if (l15==0){
      int ty = input[(b0+r)*TT + j+1];
      if (ty != 0){
        float lty = lgt[r][ty];
        nll[b0+r] += m + __logf(pe) - lty;
      }
    }
  }
}

__global__ __launch_bounds__(256) void k_loss(const float* __restrict__ nll,
                                              float* __restrict__ out)
{
  __shared__ float sm[256];
  int tid=threadIdx.x;
  float s = nll[tid] + nll[tid+256];
  sm[tid]=s; __syncthreads();
  for (int off=128; off; off>>=1){
    if (tid<off) sm[tid]+=sm[tid+off];
    __syncthreads();
  }
  if (tid==0) out[0]=sm[0];
}

extern "C" void kernel_launch(void* const* d_in, const int* in_sizes, int n_in,
                              void* d_out, int out_size, void* d_ws, size_t ws_size,
                              hipStream_t stream)
{
  const int*   input    = (const int*)  d_in[0];
  const float* src_emb  = (const float*)d_in[1];
  const float* trg_emb  = (const float*)d_in[2];
  const float* eWih_f   = (const float*)d_in[3];
  const float* eWhh_f   = (const float*)d_in[4];
  const float* ebih_f   = (const float*)d_in[5];
  const float* ebhh_f   = (const float*)d_in[6];
  const float* eWih_b   = (const float*)d_in[7];
  const float* eWhh_b   = (const float*)d_in[8];
  const float* ebih_b   = (const float*)d_in[9];
  const float* ebhh_b   = (const float*)d_in[10];
  const float* bridge_W = (const float*)d_in[11];
  const float* bridge_b = (const float*)d_in[12];
  const float* attn_Wk  = (const float*)d_in[13];
  const float* attn_Wq  = (const float*)d_in[14];
  const float* attn_We  = (const float*)d_in[15];
  const float* dec_Wih  = (const float*)d_in[16];
  const float* dec_Whh  = (const float*)d_in[17];
  const float* dec_bih  = (const float*)d_in[18];
  const float* dec_bhh  = (const float*)d_in[19];
  const float* pre_W    = (const float*)d_in[20];
  const float* gen_W    = (const float*)d_in[21];

  float* F = (float*)d_ws;
  size_t o=0;
  float* tab_gi_f = F+o; o+=(size_t)VV*H3;
  float* tab_gi_b = F+o; o+=(size_t)VV*H3;
  float* tab_dec  = F+o; o+=(size_t)VV*H3;
  float* tab_pre  = F+o; o+=(size_t)VV*HH;
  float* h_f      = F+o; o+=(size_t)BB*HH;
  float* h_b      = F+o; o+=(size_t)BB*HH;
  float* hst      = F+o; o+=(size_t)BB*HH;
  float* qg       = F+o; o+=(size_t)BB*HH;
  float* ghg      = F+o; o+=(size_t)BB*H3;
  float* nll      = F+o; o+=(size_t)BB;
  u16* U = (u16*)(F+o);
  size_t uo=0;
  u16* enc_out = U+uo; uo+=(size_t)BB*TT*H2;
  u16* pk      = U+uo; uo+=(size_t)BB*TT*HH;
  u16* ctx_bf  = U+uo; uo+=(size_t)BB*H2;
  u16* wb_ehh_f= U+uo; uo+=(size_t)H3*HH;
  u16* wb_ehh_b= U+uo; uo+=(size_t)H3*HH;
  u16* wb_dhh  = U+uo; uo+=(size_t)H3*HH;
  u16* wb_dih  = U+uo; uo+=(size_t)H3*H2;
  u16* wb_wk   = U+uo; uo+=(size_t)HH*H2;
  u16* wb_wq   = U+uo; uo+=(size_t)HH*HH;
  u16* wb_ph   = U+uo; uo+=(size_t)HH*HH;
  u16* wb_pc   = U+uo; uo+=(size_t)HH*H2;
  u16* wb_gen  = U+uo; uo+=(size_t)64*HH;

  dim3 blk(256,1,1);
  k_tables<<<dim3(VV,10),blk,0,stream>>>(src_emb,trg_emb,eWih_f,ebih_f,eWih_b,ebih_b,
                                         dec_Wih,dec_bih,pre_W,
                                         tab_gi_f,tab_gi_b,tab_dec,tab_pre);
  k_cvt_all<<<dim3(5440),blk,0,stream>>>(eWhh_f,eWhh_b,dec_Whh,dec_Wih,attn_Wk,attn_Wq,pre_W,gen_W,
                                         wb_ehh_f,wb_ehh_b,wb_dhh,wb_dih,wb_wk,wb_wq,
                                         wb_ph,wb_pc,wb_gen);
  k_enc_all<<<dim3(32),dim3(512),0,stream>>>(input,wb_ehh_f,wb_ehh_b,ebhh_f,ebhh_b,
                                             tab_gi_f,tab_gi_b,h_f,h_b,enc_out);
  k_pk<<<dim3(1024),blk,0,stream>>>(enc_out,wb_wk,pk);
  k_bridge<<<dim3(4,8),blk,0,stream>>>(h_f,h_b,bridge_W,bridge_b,hst);
  k_boot<<<dim3(32),blk,0,stream>>>(hst,wb_dhh,wb_wq,ghg,qg,nll);

  for (int j=0;j<TM1;j++){
    k_attn<<<dim3(BB),dim3(512),0,stream>>>(input,qg,pk,enc_out,attn_We,ctx_bf);
    k_dstep<<<dim3(32),blk,0,stream>>>(j,input,tab_dec,tab_pre,dec_bhh,
                                       wb_dhh,wb_dih,wb_wq,wb_ph,wb_pc,wb_gen,
                                       ctx_bf,hst,qg,ghg,nll);
  }
  k_loss<<<dim3(1),blk,0,stream>>>(nll,(float*)d_out);
}